// Round 7
// baseline (844.029 us; speedup 1.0000x reference)
//
#include <hip/hip_runtime.h>
#include <hip/hip_fp16.h>

typedef _Float16 f16;
typedef _Float16 f16x4 __attribute__((ext_vector_type(4)));
typedef _Float16 f16x8 __attribute__((ext_vector_type(8)));
typedef float f32x4 __attribute__((ext_vector_type(4)));

#define MFMA16(a, b, c) __builtin_amdgcn_mfma_f32_16x16x32_f16((a), (b), (c), 0, 0, 0)

#define FLAG_CAP (1024 * 1024)
#define FLAG_TOL 1e-3f

// async global->LDS, 16 B per lane. LDS dest is wave-uniform base; HW writes
// base + laneid*16. Global src is per-lane (swizzle is baked into the source).
__device__ __forceinline__ void gld16(const f16* g, f16* l) {
    __builtin_amdgcn_global_load_lds(
        (const __attribute__((address_space(1))) unsigned int*)g,
        (__attribute__((address_space(3))) unsigned int*)l,
        16, 0, 0);
}

// ---------------- scale computation ----------------

__global__ void k_zero(float* p, int* cnt) {
    if (threadIdx.x < 3) p[threadIdx.x] = 0.f;
    if (threadIdx.x == 3) { cnt[0] = 0; cnt[1] = 0; }
}

__global__ void k_absmax(const float* __restrict__ w, int n, float* __restrict__ out) {
    float m = 0.f;
    int stride = gridDim.x * blockDim.x;
    for (int i = blockIdx.x * blockDim.x + threadIdx.x; i < n; i += stride)
        m = fmaxf(m, fabsf(w[i]));
    #pragma unroll
    for (int o = 32; o > 0; o >>= 1) m = fmaxf(m, __shfl_down(m, o));
    __shared__ float sm[4];
    int lane = threadIdx.x & 63, wv = threadIdx.x >> 6;
    if (lane == 0) sm[wv] = m;
    __syncthreads();
    if (threadIdx.x == 0) {
        float mm = fmaxf(fmaxf(sm[0], sm[1]), fmaxf(sm[2], sm[3]));
        atomicMax((unsigned int*)out, __float_as_uint(mm));  // nonneg floats only
    }
}

// W1 quant: compact q1 (fallback), fp32 dequant w1dq (fixup), duplicated+padded
// B panel q1p [512][1664] = [q|0pad | q|0pad]. fp32 ops replicate numpy.
__global__ void k_quantw1p(const float* __restrict__ w, const float* __restrict__ wmax,
                           f16* __restrict__ q1, float* __restrict__ wdq,
                           f16* __restrict__ q1p) {
    int i = blockIdx.x * blockDim.x + threadIdx.x;
    if (i >= 512 * 832) return;
    int n = i / 832, k = i - n * 832;
    float v = 0.f;
    if (k < 784) {
        float s = wmax[0] / 7.0f + 1e-8f;
        v = rintf(w[n * 784 + k] / s);
        v = fminf(fmaxf(v, -7.f), 7.f);
        q1[n * 784 + k] = (f16)v;
        wdq[n * 784 + k] = v * s;
    }
    q1p[(size_t)n * 1664 + k] = (f16)v;
    q1p[(size_t)n * 1664 + 832 + k] = (f16)v;
}

__global__ void k_quantw(const float* __restrict__ w, const float* __restrict__ wmax,
                         f16* __restrict__ q, float* __restrict__ wdq, int n) {
    float s = wmax[0] / 7.0f + 1e-8f;
    int i = blockIdx.x * blockDim.x + threadIdx.x;
    if (i < n) {
        float v = rintf(w[i] / s);
        v = fminf(fmaxf(v, -7.f), 7.f);
        q[i] = (f16)v;
        if (wdq) wdq[i] = v * s;
    }
}

__global__ void k_quantw3(const float* __restrict__ w, const float* __restrict__ wmax,
                          f16* __restrict__ q) {
    float s = wmax[0] / 7.0f + 1e-8f;
    int i = blockIdx.x * blockDim.x + threadIdx.x;
    if (i < 16 * 512) {
        float v = 0.f;
        if (i < 10 * 512) {
            v = rintf(w[i] / s);
            v = fminf(fmaxf(v, -7.f), 7.f);
        }
        q[i] = (f16)v;
    }
}

// ---------------- prep: split X fp32 -> [hi(832) | lo(832)] f16, zero-padded ----------------

__global__ void k_prep(const float* __restrict__ X, f16* __restrict__ Xs) {
    int row = blockIdx.x;
    int p = threadIdx.x;
    if (p >= 208) return;
    f16x4 h0 = (f16x4){0, 0, 0, 0}, h1 = (f16x4){0, 0, 0, 0};
    if (p < 196) {
        float4 v = *reinterpret_cast<const float4*>(X + (size_t)row * 784 + p * 4);
        float vv[4] = {v.x, v.y, v.z, v.w};
        #pragma unroll
        for (int j = 0; j < 4; ++j) {
            f16 c0 = (f16)vv[j];                 // RNE
            h0[j] = c0;
            h1[j] = (f16)(vv[j] - (float)c0);    // exact residual
        }
    }
    *reinterpret_cast<f16x4*>(Xs + (size_t)row * 1664 + p * 4) = h0;
    *reinterpret_cast<f16x4*>(Xs + (size_t)row * 1664 + 832 + p * 4) = h1;
}

// ================= 256x256 tile, BK=32, 2-phase dbuf, 512 threads ==================
// LDS element (r,c): slot (c>>3) stored at slot (c>>3)^((r>>1)&3) -> 2-way banks (free).
// Write-side swizzle on global source (gld16 LDS dest is linear).
// Wave tile 64x128: waves (wr=w>>1 in 0..3, wc=w&1 in 0..1); acc[4][8].

__global__ __launch_bounds__(512, 2) void k_gemm1n(
    const f16* __restrict__ A, const f16* __restrict__ B,
    const float* __restrict__ wmax, const float* __restrict__ s1p,
    f16* __restrict__ A1, int* __restrict__ flagCnt, unsigned* __restrict__ flagList)
{
    constexpr int KP = 1664;
    constexpr int NT = KP / 32;              // 52 K-tiles
    __shared__ __align__(16) f16 As[2][256 * 32];
    __shared__ __align__(16) f16 Bs[2][256 * 32];

    const int t = threadIdx.x;
    const int lane = t & 63, w = t >> 6;     // 8 waves
    const int wr = w >> 1, wc = w & 1;

    // XCD chunking: pairs of lg share an A row-panel on one XCD
    const int bid = blockIdx.x;              // 512 blocks
    const int lg = (bid & 7) * 64 + (bid >> 3);
    const int n0 = (lg & 1) * 256;
    const int row0 = (lg >> 1) * 256;

    f32x4 acc[4][8];
    #pragma unroll
    for (int m = 0; m < 4; ++m)
        #pragma unroll
        for (int n = 0; n < 8; ++n) acc[m][n] = (f32x4){0.f, 0.f, 0.f, 0.f};

    // staging lane map: row-in-chunk = lane>>2, global slot = (lane&3)^((lane>>3)&3)
    const int slr = lane >> 2;
    const int sgc = ((lane & 3) ^ ((lane >> 3) & 3)) * 8;
    const f16* Ab = A + (size_t)(row0 + slr) * KP + sgc;
    const f16* Bb = B + (size_t)(n0 + slr) * KP + sgc;

    auto STAGE = [&](int buf, int k0) {
        #pragma unroll
        for (int i = 0; i < 2; ++i) {
            int ch = w * 2 + i;              // 16 chunks x 16 rows = 256 rows
            gld16(Ab + (size_t)ch * 16 * KP + k0, &As[buf][ch * 512]);
            gld16(Bb + (size_t)ch * 16 * KP + k0, &Bs[buf][ch * 512]);
        }
    };

    const int l15 = lane & 15;
    const int soff = (((lane >> 4) ^ ((l15 >> 1) & 3)) * 8);  // read-side swizzled col

    auto COMPUTE = [&](int buf) {
        f16x8 af[4], bf[8];
        #pragma unroll
        for (int m = 0; m < 4; ++m)
            af[m] = *reinterpret_cast<const f16x8*>(&As[buf][(wr * 64 + m * 16 + l15) * 32 + soff]);
        #pragma unroll
        for (int n = 0; n < 8; ++n)
            bf[n] = *reinterpret_cast<const f16x8*>(&Bs[buf][(wc * 128 + n * 16 + l15) * 32 + soff]);
        #pragma unroll
        for (int m = 0; m < 4; ++m)
            #pragma unroll
            for (int n = 0; n < 8; ++n)
                acc[m][n] = MFMA16(af[m], bf[n], acc[m][n]);
    };

    STAGE(0, 0);
    __syncthreads();
    for (int tt = 0; tt < NT; ++tt) {
        if (tt + 1 < NT) STAGE((tt + 1) & 1, (tt + 1) * 32);  // loads fly under compute
        COMPUTE(tt & 1);
        __syncthreads();                                       // vmcnt drain after compute
    }

    float sw = wmax[0] / 7.0f + 1e-8f;
    float s1v = s1p[0];
    #pragma unroll
    for (int m = 0; m < 4; ++m)
        #pragma unroll
        for (int n = 0; n < 8; ++n)
            #pragma unroll
            for (int j = 0; j < 4; ++j) {
                int row = row0 + wr * 64 + m * 16 + (lane >> 4) * 4 + j;
                int col = n0 + wc * 128 + n * 16 + l15;
                float h = sw * acc[m][n][j];
                float r = fmaxf(h, 0.f) / s1v;
                float qv = fminf(rintf(r), 15.f);
                A1[(size_t)row * 512 + col] = (f16)qv;
                float fr = r - floorf(r);
                if (fabsf(fr - 0.5f) < FLAG_TOL) {
                    int p = atomicAdd(flagCnt, 1);
                    if (p < FLAG_CAP) flagList[p] = (unsigned)(row * 512 + col);
                }
            }
}

__global__ __launch_bounds__(512, 2) void k_gemm2n(
    const f16* __restrict__ A, const f16* __restrict__ B,
    const float* __restrict__ wmax, const float* __restrict__ s1p, const float* __restrict__ s2p,
    f16* __restrict__ A2, int* __restrict__ flagCnt, unsigned* __restrict__ flagList)
{
    constexpr int KP = 512;
    constexpr int NT = KP / 32;              // 16 K-tiles
    __shared__ __align__(16) f16 As[2][256 * 32];
    __shared__ __align__(16) f16 Bs[2][256 * 32];

    const int t = threadIdx.x;
    const int lane = t & 63, w = t >> 6;
    const int wr = w >> 1, wc = w & 1;

    const int bid = blockIdx.x;
    const int lg = (bid & 7) * 64 + (bid >> 3);
    const int n0 = (lg & 1) * 256;
    const int row0 = (lg >> 1) * 256;

    f32x4 acc[4][8];
    #pragma unroll
    for (int m = 0; m < 4; ++m)
        #pragma unroll
        for (int n = 0; n < 8; ++n) acc[m][n] = (f32x4){0.f, 0.f, 0.f, 0.f};

    const int slr = lane >> 2;
    const int sgc = ((lane & 3) ^ ((lane >> 3) & 3)) * 8;
    const f16* Ab = A + (size_t)(row0 + slr) * KP + sgc;
    const f16* Bb = B + (size_t)(n0 + slr) * KP + sgc;

    auto STAGE = [&](int buf, int k0) {
        #pragma unroll
        for (int i = 0; i < 2; ++i) {
            int ch = w * 2 + i;
            gld16(Ab + (size_t)ch * 16 * KP + k0, &As[buf][ch * 512]);
            gld16(Bb + (size_t)ch * 16 * KP + k0, &Bs[buf][ch * 512]);
        }
    };

    const int l15 = lane & 15;
    const int soff = (((lane >> 4) ^ ((l15 >> 1) & 3)) * 8);

    auto COMPUTE = [&](int buf) {
        f16x8 af[4], bf[8];
        #pragma unroll
        for (int m = 0; m < 4; ++m)
            af[m] = *reinterpret_cast<const f16x8*>(&As[buf][(wr * 64 + m * 16 + l15) * 32 + soff]);
        #pragma unroll
        for (int n = 0; n < 8; ++n)
            bf[n] = *reinterpret_cast<const f16x8*>(&Bs[buf][(wc * 128 + n * 16 + l15) * 32 + soff]);
        #pragma unroll
        for (int m = 0; m < 4; ++m)
            #pragma unroll
            for (int n = 0; n < 8; ++n)
                acc[m][n] = MFMA16(af[m], bf[n], acc[m][n]);
    };

    STAGE(0, 0);
    __syncthreads();
    for (int tt = 0; tt < NT; ++tt) {
        if (tt + 1 < NT) STAGE((tt + 1) & 1, (tt + 1) * 32);
        COMPUTE(tt & 1);
        __syncthreads();
    }

    double cs = (double)s1p[0] * (double)(wmax[0] / 7.0f + 1e-8f);
    double s2v = (double)s2p[0];
    #pragma unroll
    for (int m = 0; m < 4; ++m)
        #pragma unroll
        for (int n = 0; n < 8; ++n)
            #pragma unroll
            for (int j = 0; j < 4; ++j) {
                int row = row0 + wr * 64 + m * 16 + (lane >> 4) * 4 + j;
                int col = n0 + wc * 128 + n * 16 + l15;
                double r = fmax((double)acc[m][n][j] * cs, 0.0) / s2v;
                double qv = fmin(rint(r), 15.0);
                A2[(size_t)row * 512 + col] = (f16)qv;
                double fr = r - floor(r);
                if (fabs(fr - 0.5) < (double)FLAG_TOL && r < 16.0) {
                    int p = atomicAdd(flagCnt, 1);
                    if (p < FLAG_CAP) flagList[p] = (unsigned)(row * 512 + col);
                }
            }
}

// ---------------- fallback GEMM1 (round-3, in-kernel split) ----------------

__global__ __launch_bounds__(256) void k_gemm1s(
    const float* __restrict__ X, const f16* __restrict__ Q1,
    const float* __restrict__ wmax, const float* __restrict__ s1p,
    f16* __restrict__ A1, int* __restrict__ flagCnt, unsigned* __restrict__ flagList)
{
    __shared__ __align__(16) f16 As0[128][72];
    __shared__ __align__(16) f16 As1[128][72];
    __shared__ __align__(16) f16 Bs[128][72];

    const int t = threadIdx.x;
    const int row0 = blockIdx.y * 128;
    const int n0 = blockIdx.x * 128;
    const int lane = t & 63, wv = t >> 6;
    const int wr = wv >> 1, wc = wv & 1;

    f32x4 acc[4][4];
    #pragma unroll
    for (int m = 0; m < 4; ++m)
        #pragma unroll
        for (int n = 0; n < 4; ++n) acc[m][n] = (f32x4){0.f, 0.f, 0.f, 0.f};

    for (int k0 = 0; k0 < 784; k0 += 64) {
        #pragma unroll
        for (int i = 0; i < 8; ++i) {
            int f = t + 256 * i;
            int r = f >> 4, c = f & 15;
            int gk = k0 + c * 4;
            float4 v = make_float4(0.f, 0.f, 0.f, 0.f);
            if (gk < 784)
                v = *reinterpret_cast<const float4*>(X + (size_t)(row0 + r) * 784 + gk);
            float vv[4] = {v.x, v.y, v.z, v.w};
            f16x4 h0, h1;
            #pragma unroll
            for (int j = 0; j < 4; ++j) {
                f16 c0 = (f16)vv[j];
                h0[j] = c0;
                h1[j] = (f16)(vv[j] - (float)c0);
            }
            *reinterpret_cast<f16x4*>(&As0[r][c * 4]) = h0;
            *reinterpret_cast<f16x4*>(&As1[r][c * 4]) = h1;
        }
        #pragma unroll
        for (int i = 0; i < 4; ++i) {
            int f = t + 256 * i;
            int r = f >> 3, c = f & 7;
            int gk = k0 + c * 8;
            uint4 u = make_uint4(0u, 0u, 0u, 0u);
            if (gk < 784)
                u = *reinterpret_cast<const uint4*>(Q1 + (size_t)(n0 + r) * 784 + gk);
            *reinterpret_cast<uint4*>(&Bs[r][c * 8]) = u;
        }
        __syncthreads();

        #pragma unroll
        for (int kk = 0; kk < 2; ++kk) {
            int kb = kk * 32 + (lane >> 4) * 8;
            f16x8 bf[4], a0[4], a1f[4];
            #pragma unroll
            for (int n = 0; n < 4; ++n)
                bf[n] = *reinterpret_cast<const f16x8*>(&Bs[wc * 64 + n * 16 + (lane & 15)][kb]);
            #pragma unroll
            for (int m = 0; m < 4; ++m) {
                a0[m]  = *reinterpret_cast<const f16x8*>(&As0[wr * 64 + m * 16 + (lane & 15)][kb]);
                a1f[m] = *reinterpret_cast<const f16x8*>(&As1[wr * 64 + m * 16 + (lane & 15)][kb]);
            }
            #pragma unroll
            for (int m = 0; m < 4; ++m)
                #pragma unroll
                for (int n = 0; n < 4; ++n) {
                    acc[m][n] = MFMA16(a0[m],  bf[n], acc[m][n]);
                    acc[m][n] = MFMA16(a1f[m], bf[n], acc[m][n]);
                }
        }
        __syncthreads();
    }

    float sw = wmax[0] / 7.0f + 1e-8f;
    float s1v = s1p[0];
    #pragma unroll
    for (int m = 0; m < 4; ++m)
        #pragma unroll
        for (int n = 0; n < 4; ++n)
            #pragma unroll
            for (int j = 0; j < 4; ++j) {
                int row = row0 + wr * 64 + m * 16 + (lane >> 4) * 4 + j;
                int col = n0 + wc * 64 + n * 16 + (lane & 15);
                float h = sw * acc[m][n][j];
                float r = fmaxf(h, 0.f) / s1v;
                float qv = fminf(rintf(r), 15.f);
                A1[(size_t)row * 512 + col] = (f16)qv;
                float fr = r - floorf(r);
                if (fabsf(fr - 0.5f) < FLAG_TOL) {
                    int p = atomicAdd(flagCnt, 1);
                    if (p < FLAG_CAP) flagList[p] = (unsigned)(row * 512 + col);
                }
            }
}

// ---------------- fixups: BLAS-replicating sequential fp32 FMA ----------------

__global__ void k_fixup1(const float* __restrict__ X, const float* __restrict__ W1dq,
                         const float* __restrict__ s1p,
                         const int* __restrict__ flagCnt, const unsigned* __restrict__ flagList,
                         f16* __restrict__ A1)
{
    int tid = blockIdx.x * blockDim.x + threadIdx.x;
    int nthr = gridDim.x * blockDim.x;
    int n = flagCnt[0];
    if (n > FLAG_CAP) n = FLAG_CAP;
    float s1 = s1p[0];
    for (int i = tid; i < n; i += nthr) {
        unsigned idx = flagList[i];
        int row = (int)(idx >> 9), col = (int)(idx & 511);
        const float* xr = X + (size_t)row * 784;
        const float* wr = W1dq + (size_t)col * 784;
        float acc = 0.f;
        for (int k = 0; k < 784; ++k)
            acc = fmaf(xr[k], wr[k], acc);
        float tq = fmaxf(acc, 0.f) / s1;
        float code = fminf(rintf(tq), 15.f);
        A1[(size_t)row * 512 + col] = (f16)code;
    }
}

__global__ void k_fixup2(const f16* __restrict__ A1, const float* __restrict__ W2dq,
                         const float* __restrict__ s1p, const float* __restrict__ s2p,
                         const int* __restrict__ flagCnt, const unsigned* __restrict__ flagList,
                         f16* __restrict__ A2)
{
    int tid = blockIdx.x * blockDim.x + threadIdx.x;
    int nthr = gridDim.x * blockDim.x;
    int n = flagCnt[0];
    if (n > FLAG_CAP) n = FLAG_CAP;
    float s1 = s1p[0], s2 = s2p[0];
    for (int i = tid; i < n; i += nthr) {
        unsigned idx = flagList[i];
        int row = (int)(idx >> 9), col = (int)(idx & 511);
        const f16* ar = A1 + (size_t)row * 512;
        const float* wr = W2dq + (size_t)col * 512;
        float acc = 0.f;
        for (int k = 0; k < 512; ++k) {
            float adq = (float)ar[k] * s1;
            acc = fmaf(adq, wr[k], acc);
        }
        float tq = fmaxf(acc, 0.f) / s2;
        float code = fminf(rintf(tq), 15.f);
        A2[(size_t)row * 512 + col] = (f16)code;
    }
}

// ---------------- GEMM3: [65536,512] @ [16,512]^T -> fp32 logits ----------------

__global__ __launch_bounds__(256) void k_gemm3(
    const f16* __restrict__ A2, const f16* __restrict__ Q3,
    const float* __restrict__ wmax, const float* __restrict__ s2p,
    float* __restrict__ Out)
{
    __shared__ __align__(16) f16 As[256][72];
    __shared__ __align__(16) f16 Bs[16][72];

    const int t = threadIdx.x;
    const int row0 = blockIdx.x * 256;
    const int lane = t & 63, wv = t >> 6;

    f32x4 acc[4];
    #pragma unroll
    for (int m = 0; m < 4; ++m) acc[m] = (f32x4){0.f, 0.f, 0.f, 0.f};

    for (int k0 = 0; k0 < 512; k0 += 64) {
        #pragma unroll
        for (int i = 0; i < 8; ++i) {
            int f = t + 256 * i;
            int r = f >> 3, c = f & 7;
            *reinterpret_cast<uint4*>(&As[r][c * 8]) =
                *reinterpret_cast<const uint4*>(A2 + (size_t)(row0 + r) * 512 + k0 + c * 8);
        }
        if (t < 128) {
            int r = t >> 3, c = t & 7;
            *reinterpret_cast<uint4*>(&Bs[r][c * 8]) =
                *reinterpret_cast<const uint4*>(Q3 + (size_t)r * 512 + k0 + c * 8);
        }
        __syncthreads();

        #pragma unroll
        for (int kk = 0; kk < 2; ++kk) {
            int kb = kk * 32 + (lane >> 4) * 8;
            f16x8 bf = *reinterpret_cast<const f16x8*>(&Bs[lane & 15][kb]);
            #pragma unroll
            for (int m = 0; m < 4; ++m) {
                f16x8 af = *reinterpret_cast<const f16x8*>(&As[wv * 64 + m * 16 + (lane & 15)][kb]);
                acc[m] = MFMA16(af, bf, acc[m]);
            }
        }
        __syncthreads();
    }

    double cs = (double)s2p[0] * (double)(wmax[0] / 7.0f + 1e-8f);
    #pragma unroll
    for (int m = 0; m < 4; ++m)
        #pragma unroll
        for (int j = 0; j < 4; ++j) {
            int row = row0 + wv * 64 + m * 16 + (lane >> 4) * 4 + j;
            int col = lane & 15;
            if (col < 10)
                Out[(size_t)row * 10 + col] = (float)((double)acc[m][j] * cs);
        }
}

// ---------------- launch ----------------

extern "C" void kernel_launch(void* const* d_in, const int* in_sizes, int n_in,
                              void* d_out, int out_size, void* d_ws, size_t ws_size,
                              hipStream_t stream)
{
    (void)in_sizes; (void)n_in; (void)out_size;

    const float* X  = (const float*)d_in[0];
    const float* W1 = (const float*)d_in[1];
    const float* W2 = (const float*)d_in[2];
    const float* W3 = (const float*)d_in[3];
    const float* s1 = (const float*)d_in[4];
    const float* s2 = (const float*)d_in[5];
    float* Out = (float*)d_out;

    char* ws = (char*)d_ws;
    float* maxes   = (float*)ws;
    int*   cnts    = (int*)(ws + 16);
    f16*   q1      = (f16*)(ws + 4096);                           // 802816 B
    f16*   q2      = (f16*)(ws + (size_t)(1u << 20));             // 524288 B
    f16*   q3      = (f16*)(ws + (size_t)(1u << 20) + 600000);    // 16384 B
    f16*   q1p     = (f16*)(ws + (size_t)(2u << 20));             // 1703936 B
    float* w1dq    = (float*)(ws + (size_t)(4u << 20));           // 1605632 B
    float* w2dq    = (float*)(ws + (size_t)(6u << 20));           // 1048576 B
    f16*   a1      = (f16*)(ws + (size_t)(8u << 20));             // 64 MB
    f16*   a2      = (f16*)(ws + (size_t)(72u << 20));            // 64 MB
    unsigned* fl1  = (unsigned*)(ws + (size_t)(136u << 20));      // 4 MB
    unsigned* fl2  = (unsigned*)(ws + (size_t)(140u << 20));      // 4 MB
    f16*   Xs      = (f16*)(ws + (size_t)(144u << 20));           // 218 MB (fast path)

    const bool big = ws_size >= ((size_t)356 << 20);

    k_zero<<<1, 64, 0, stream>>>(maxes, cnts);
    k_absmax<<<256, 256, 0, stream>>>(W1, 512 * 784, maxes + 0);
    k_absmax<<<256, 256, 0, stream>>>(W2, 512 * 512, maxes + 1);
    k_absmax<<<8, 256, 0, stream>>>(W3, 10 * 512, maxes + 2);
    k_quantw1p<<<(512 * 832 + 255) / 256, 256, 0, stream>>>(W1, maxes + 0, q1, w1dq, q1p);
    k_quantw<<<(512 * 512 + 255) / 256, 256, 0, stream>>>(W2, maxes + 1, q2, w2dq, 512 * 512);
    k_quantw3<<<(16 * 512 + 255) / 256, 256, 0, stream>>>(W3, maxes + 2, q3);

    if (big) {
        k_prep<<<65536, 256, 0, stream>>>(X, Xs);
        k_gemm1n<<<512, 512, 0, stream>>>(Xs, q1p, maxes + 0, s1, a1, cnts + 0, fl1);
    } else {
        k_gemm1s<<<dim3(4, 512), 256, 0, stream>>>(X, q1, maxes + 0, s1, a1, cnts + 0, fl1);
    }
    k_fixup1<<<512, 256, 0, stream>>>(X, w1dq, s1, cnts + 0, fl1, a1);
    k_gemm2n<<<512, 512, 0, stream>>>(a1, q2, maxes + 1, s1, s2, a2, cnts + 1, fl2);
    k_fixup2<<<512, 256, 0, stream>>>(a1, w2dq, s1, s2, cnts + 1, fl2, a2);
    k_gemm3<<<256, 256, 0, stream>>>(a2, q3, maxes + 2, s2, Out);
}

// Round 8
// 755.292 us; speedup vs baseline: 1.1175x; 1.1175x over previous
//
#include <hip/hip_runtime.h>
#include <hip/hip_fp16.h>

typedef _Float16 f16;
typedef _Float16 f16x4 __attribute__((ext_vector_type(4)));
typedef _Float16 f16x8 __attribute__((ext_vector_type(8)));
typedef float f32x4 __attribute__((ext_vector_type(4)));

#define MFMA16(a, b, c) __builtin_amdgcn_mfma_f32_16x16x32_f16((a), (b), (c), 0, 0, 0)

#define FLAG_CAP (1024 * 1024)
#define FLAG_TOL 1e-3f

// async global->LDS, 16 B per lane. LDS dest is wave-uniform base; HW writes
// base + laneid*16. Global src is per-lane (swizzle is baked into the source).
__device__ __forceinline__ void gld16(const f16* g, f16* l) {
    __builtin_amdgcn_global_load_lds(
        (const __attribute__((address_space(1))) unsigned int*)g,
        (__attribute__((address_space(3))) unsigned int*)l,
        16, 0, 0);
}

// ---------------- scale computation ----------------

__global__ void k_zero(float* p, int* cnt) {
    if (threadIdx.x < 3) p[threadIdx.x] = 0.f;
    if (threadIdx.x == 3) { cnt[0] = 0; cnt[1] = 0; }
}

__global__ void k_absmax(const float* __restrict__ w, int n, float* __restrict__ out) {
    float m = 0.f;
    int stride = gridDim.x * blockDim.x;
    for (int i = blockIdx.x * blockDim.x + threadIdx.x; i < n; i += stride)
        m = fmaxf(m, fabsf(w[i]));
    #pragma unroll
    for (int o = 32; o > 0; o >>= 1) m = fmaxf(m, __shfl_down(m, o));
    __shared__ float sm[4];
    int lane = threadIdx.x & 63, wv = threadIdx.x >> 6;
    if (lane == 0) sm[wv] = m;
    __syncthreads();
    if (threadIdx.x == 0) {
        float mm = fmaxf(fmaxf(sm[0], sm[1]), fmaxf(sm[2], sm[3]));
        atomicMax((unsigned int*)out, __float_as_uint(mm));  // nonneg floats only
    }
}

// W1 quant: compact q1 (fallback), fp32 dequant w1dq (fixup), duplicated+padded
// B panel q1p [512][1664] = [q|0pad | q|0pad]. fp32 ops replicate numpy.
__global__ void k_quantw1p(const float* __restrict__ w, const float* __restrict__ wmax,
                           f16* __restrict__ q1, float* __restrict__ wdq,
                           f16* __restrict__ q1p) {
    int i = blockIdx.x * blockDim.x + threadIdx.x;
    if (i >= 512 * 832) return;
    int n = i / 832, k = i - n * 832;
    float v = 0.f;
    if (k < 784) {
        float s = wmax[0] / 7.0f + 1e-8f;
        v = rintf(w[n * 784 + k] / s);
        v = fminf(fmaxf(v, -7.f), 7.f);
        q1[n * 784 + k] = (f16)v;
        wdq[n * 784 + k] = v * s;
    }
    q1p[(size_t)n * 1664 + k] = (f16)v;
    q1p[(size_t)n * 1664 + 832 + k] = (f16)v;
}

__global__ void k_quantw(const float* __restrict__ w, const float* __restrict__ wmax,
                         f16* __restrict__ q, float* __restrict__ wdq, int n) {
    float s = wmax[0] / 7.0f + 1e-8f;
    int i = blockIdx.x * blockDim.x + threadIdx.x;
    if (i < n) {
        float v = rintf(w[i] / s);
        v = fminf(fmaxf(v, -7.f), 7.f);
        q[i] = (f16)v;
        if (wdq) wdq[i] = v * s;
    }
}

__global__ void k_quantw3(const float* __restrict__ w, const float* __restrict__ wmax,
                          f16* __restrict__ q) {
    float s = wmax[0] / 7.0f + 1e-8f;
    int i = blockIdx.x * blockDim.x + threadIdx.x;
    if (i < 16 * 512) {
        float v = 0.f;
        if (i < 10 * 512) {
            v = rintf(w[i] / s);
            v = fminf(fmaxf(v, -7.f), 7.f);
        }
        q[i] = (f16)v;
    }
}

// ---------------- prep: split X fp32 -> [hi(832) | lo(832)] f16, zero-padded ----------------

__global__ void k_prep(const float* __restrict__ X, f16* __restrict__ Xs) {
    int row = blockIdx.x;
    int p = threadIdx.x;
    if (p >= 208) return;
    f16x4 h0 = (f16x4){0, 0, 0, 0}, h1 = (f16x4){0, 0, 0, 0};
    if (p < 196) {
        float4 v = *reinterpret_cast<const float4*>(X + (size_t)row * 784 + p * 4);
        float vv[4] = {v.x, v.y, v.z, v.w};
        #pragma unroll
        for (int j = 0; j < 4; ++j) {
            f16 c0 = (f16)vv[j];                 // RNE
            h0[j] = c0;
            h1[j] = (f16)(vv[j] - (float)c0);    // exact residual
        }
    }
    *reinterpret_cast<f16x4*>(Xs + (size_t)row * 1664 + p * 4) = h0;
    *reinterpret_cast<f16x4*>(Xs + (size_t)row * 1664 + 832 + p * 4) = h1;
}

// ========== pipelined GEMM: 128x128 tile, BK=64, dbuf + COUNTED vmcnt ==========
// Raw s_barrier + "s_waitcnt vmcnt(8)": each wave waits only for its OWN 8
// older loads (the 8 newest belong to the other buffer), so next-tile loads
// stay in flight ACROSS both barriers (T4; m218). LDS swizzle as round 6:
// element (r,c) stored at slot (c>>3)^(r&7), write-side via global source.

__global__ __launch_bounds__(256, 2) void k_gemm1p(
    const f16* __restrict__ A, const f16* __restrict__ B,
    const float* __restrict__ wmax, const float* __restrict__ s1p,
    f16* __restrict__ A1, int* __restrict__ flagCnt, unsigned* __restrict__ flagList)
{
    constexpr int KP = 1664;
    constexpr int NT = KP / 64;              // 26 K-tiles
    __shared__ __align__(16) f16 As[2][128 * 64];
    __shared__ __align__(16) f16 Bs[2][128 * 64];

    const int t = threadIdx.x;
    const int lane = t & 63, w = t >> 6;
    const int wr = w >> 1, wc = w & 1;

    const int bid = blockIdx.x;
    const int lg = (bid & 7) * 256 + (bid >> 3);
    const int n0 = (lg & 3) * 128;
    const int row0 = (lg >> 2) * 128;

    f32x4 acc[4][4];
    #pragma unroll
    for (int m = 0; m < 4; ++m)
        #pragma unroll
        for (int n = 0; n < 4; ++n) acc[m][n] = (f32x4){0.f, 0.f, 0.f, 0.f};

    const int lr = lane >> 3;
    const int lc = (((lane & 7) ^ (lane >> 3)) * 8);
    const f16* Ab = A + (size_t)(row0 + lr) * KP + lc;
    const f16* Bb = B + (size_t)(n0 + lr) * KP + lc;

    auto STAGE = [&](int buf, int k0) {      // 8 gld16 per wave
        #pragma unroll
        for (int i = 0; i < 4; ++i) {
            int ch = w * 4 + i;              // 16 chunks x 8 rows = 128 rows
            gld16(Ab + (size_t)ch * 8 * KP + k0, &As[buf][ch * 512]);
            gld16(Bb + (size_t)ch * 8 * KP + k0, &Bs[buf][ch * 512]);
        }
    };

    auto COMPUTE = [&](int buf) {
        #pragma unroll
        for (int kk = 0; kk < 2; ++kk) {
            int kb = kk * 32 + (lane >> 4) * 8;
            int ksw = kb ^ ((lane & 7) << 3);
            f16x8 bf[4], af[4];
            #pragma unroll
            for (int n = 0; n < 4; ++n)
                bf[n] = *reinterpret_cast<const f16x8*>(&Bs[buf][(wc * 64 + n * 16 + (lane & 15)) * 64 + ksw]);
            #pragma unroll
            for (int m = 0; m < 4; ++m)
                af[m] = *reinterpret_cast<const f16x8*>(&As[buf][(wr * 64 + m * 16 + (lane & 15)) * 64 + ksw]);
            #pragma unroll
            for (int m = 0; m < 4; ++m)
                #pragma unroll
                for (int n = 0; n < 4; ++n)
                    acc[m][n] = MFMA16(af[m], bf[n], acc[m][n]);
        }
    };

    STAGE(0, 0);
    STAGE(1, 64);                            // 16 loads in flight
    for (int tt = 0; tt < NT; ++tt) {
        if (tt == NT - 1) asm volatile("s_waitcnt vmcnt(0)" ::: "memory");
        else              asm volatile("s_waitcnt vmcnt(8)" ::: "memory");
        __builtin_amdgcn_s_barrier();        // all waves' cur-buf loads landed
        COMPUTE(tt & 1);
        __builtin_amdgcn_s_barrier();        // all waves done reading cur-buf
        if (tt + 2 < NT) STAGE(tt & 1, (tt + 2) * 64);
    }

    float sw = wmax[0] / 7.0f + 1e-8f;
    float s1v = s1p[0];
    #pragma unroll
    for (int m = 0; m < 4; ++m)
        #pragma unroll
        for (int n = 0; n < 4; ++n)
            #pragma unroll
            for (int j = 0; j < 4; ++j) {
                int row = row0 + wr * 64 + m * 16 + (lane >> 4) * 4 + j;
                int col = n0 + wc * 64 + n * 16 + (lane & 15);
                float h = sw * acc[m][n][j];
                float r = fmaxf(h, 0.f) / s1v;
                float qv = fminf(rintf(r), 15.f);
                A1[(size_t)row * 512 + col] = (f16)qv;
                float fr = r - floorf(r);
                if (fabsf(fr - 0.5f) < FLAG_TOL) {
                    int p = atomicAdd(flagCnt, 1);
                    if (p < FLAG_CAP) flagList[p] = (unsigned)(row * 512 + col);
                }
            }
}

__global__ __launch_bounds__(256, 2) void k_gemm2p(
    const f16* __restrict__ A, const f16* __restrict__ B,
    const float* __restrict__ wmax, const float* __restrict__ s1p, const float* __restrict__ s2p,
    f16* __restrict__ A2, int* __restrict__ flagCnt, unsigned* __restrict__ flagList)
{
    constexpr int KP = 512;
    constexpr int NT = KP / 64;              // 8 K-tiles
    __shared__ __align__(16) f16 As[2][128 * 64];
    __shared__ __align__(16) f16 Bs[2][128 * 64];

    const int t = threadIdx.x;
    const int lane = t & 63, w = t >> 6;
    const int wr = w >> 1, wc = w & 1;

    const int bid = blockIdx.x;
    const int lg = (bid & 7) * 256 + (bid >> 3);
    const int n0 = (lg & 3) * 128;
    const int row0 = (lg >> 2) * 128;

    f32x4 acc[4][4];
    #pragma unroll
    for (int m = 0; m < 4; ++m)
        #pragma unroll
        for (int n = 0; n < 4; ++n) acc[m][n] = (f32x4){0.f, 0.f, 0.f, 0.f};

    const int lr = lane >> 3;
    const int lc = (((lane & 7) ^ (lane >> 3)) * 8);
    const f16* Ab = A + (size_t)(row0 + lr) * KP + lc;
    const f16* Bb = B + (size_t)(n0 + lr) * KP + lc;

    auto STAGE = [&](int buf, int k0) {
        #pragma unroll
        for (int i = 0; i < 4; ++i) {
            int ch = w * 4 + i;
            gld16(Ab + (size_t)ch * 8 * KP + k0, &As[buf][ch * 512]);
            gld16(Bb + (size_t)ch * 8 * KP + k0, &Bs[buf][ch * 512]);
        }
    };

    auto COMPUTE = [&](int buf) {
        #pragma unroll
        for (int kk = 0; kk < 2; ++kk) {
            int kb = kk * 32 + (lane >> 4) * 8;
            int ksw = kb ^ ((lane & 7) << 3);
            f16x8 bf[4], af[4];
            #pragma unroll
            for (int n = 0; n < 4; ++n)
                bf[n] = *reinterpret_cast<const f16x8*>(&Bs[buf][(wc * 64 + n * 16 + (lane & 15)) * 64 + ksw]);
            #pragma unroll
            for (int m = 0; m < 4; ++m)
                af[m] = *reinterpret_cast<const f16x8*>(&As[buf][(wr * 64 + m * 16 + (lane & 15)) * 64 + ksw]);
            #pragma unroll
            for (int m = 0; m < 4; ++m)
                #pragma unroll
                for (int n = 0; n < 4; ++n)
                    acc[m][n] = MFMA16(af[m], bf[n], acc[m][n]);
        }
    };

    STAGE(0, 0);
    STAGE(1, 64);
    for (int tt = 0; tt < NT; ++tt) {
        if (tt == NT - 1) asm volatile("s_waitcnt vmcnt(0)" ::: "memory");
        else              asm volatile("s_waitcnt vmcnt(8)" ::: "memory");
        __builtin_amdgcn_s_barrier();
        COMPUTE(tt & 1);
        __builtin_amdgcn_s_barrier();
        if (tt + 2 < NT) STAGE(tt & 1, (tt + 2) * 64);
    }

    double cs = (double)s1p[0] * (double)(wmax[0] / 7.0f + 1e-8f);
    double s2v = (double)s2p[0];
    #pragma unroll
    for (int m = 0; m < 4; ++m)
        #pragma unroll
        for (int n = 0; n < 4; ++n)
            #pragma unroll
            for (int j = 0; j < 4; ++j) {
                int row = row0 + wr * 64 + m * 16 + (lane >> 4) * 4 + j;
                int col = n0 + wc * 64 + n * 16 + (lane & 15);
                double r = fmax((double)acc[m][n][j] * cs, 0.0) / s2v;
                double qv = fmin(rint(r), 15.0);
                A2[(size_t)row * 512 + col] = (f16)qv;
                double fr = r - floor(r);
                if (fabs(fr - 0.5) < (double)FLAG_TOL && r < 16.0) {
                    int p = atomicAdd(flagCnt, 1);
                    if (p < FLAG_CAP) flagList[p] = (unsigned)(row * 512 + col);
                }
            }
}

// ---------------- fallback GEMM1 (round-3, in-kernel split) ----------------

__global__ __launch_bounds__(256) void k_gemm1s(
    const float* __restrict__ X, const f16* __restrict__ Q1,
    const float* __restrict__ wmax, const float* __restrict__ s1p,
    f16* __restrict__ A1, int* __restrict__ flagCnt, unsigned* __restrict__ flagList)
{
    __shared__ __align__(16) f16 As0[128][72];
    __shared__ __align__(16) f16 As1[128][72];
    __shared__ __align__(16) f16 Bs[128][72];

    const int t = threadIdx.x;
    const int row0 = blockIdx.y * 128;
    const int n0 = blockIdx.x * 128;
    const int lane = t & 63, wv = t >> 6;
    const int wr = wv >> 1, wc = wv & 1;

    f32x4 acc[4][4];
    #pragma unroll
    for (int m = 0; m < 4; ++m)
        #pragma unroll
        for (int n = 0; n < 4; ++n) acc[m][n] = (f32x4){0.f, 0.f, 0.f, 0.f};

    for (int k0 = 0; k0 < 784; k0 += 64) {
        #pragma unroll
        for (int i = 0; i < 8; ++i) {
            int f = t + 256 * i;
            int r = f >> 4, c = f & 15;
            int gk = k0 + c * 4;
            float4 v = make_float4(0.f, 0.f, 0.f, 0.f);
            if (gk < 784)
                v = *reinterpret_cast<const float4*>(X + (size_t)(row0 + r) * 784 + gk);
            float vv[4] = {v.x, v.y, v.z, v.w};
            f16x4 h0, h1;
            #pragma unroll
            for (int j = 0; j < 4; ++j) {
                f16 c0 = (f16)vv[j];
                h0[j] = c0;
                h1[j] = (f16)(vv[j] - (float)c0);
            }
            *reinterpret_cast<f16x4*>(&As0[r][c * 4]) = h0;
            *reinterpret_cast<f16x4*>(&As1[r][c * 4]) = h1;
        }
        #pragma unroll
        for (int i = 0; i < 4; ++i) {
            int f = t + 256 * i;
            int r = f >> 3, c = f & 7;
            int gk = k0 + c * 8;
            uint4 u = make_uint4(0u, 0u, 0u, 0u);
            if (gk < 784)
                u = *reinterpret_cast<const uint4*>(Q1 + (size_t)(n0 + r) * 784 + gk);
            *reinterpret_cast<uint4*>(&Bs[r][c * 8]) = u;
        }
        __syncthreads();

        #pragma unroll
        for (int kk = 0; kk < 2; ++kk) {
            int kb = kk * 32 + (lane >> 4) * 8;
            f16x8 bf[4], a0[4], a1f[4];
            #pragma unroll
            for (int n = 0; n < 4; ++n)
                bf[n] = *reinterpret_cast<const f16x8*>(&Bs[wc * 64 + n * 16 + (lane & 15)][kb]);
            #pragma unroll
            for (int m = 0; m < 4; ++m) {
                a0[m]  = *reinterpret_cast<const f16x8*>(&As0[wr * 64 + m * 16 + (lane & 15)][kb]);
                a1f[m] = *reinterpret_cast<const f16x8*>(&As1[wr * 64 + m * 16 + (lane & 15)][kb]);
            }
            #pragma unroll
            for (int m = 0; m < 4; ++m)
                #pragma unroll
                for (int n = 0; n < 4; ++n) {
                    acc[m][n] = MFMA16(a0[m],  bf[n], acc[m][n]);
                    acc[m][n] = MFMA16(a1f[m], bf[n], acc[m][n]);
                }
        }
        __syncthreads();
    }

    float sw = wmax[0] / 7.0f + 1e-8f;
    float s1v = s1p[0];
    #pragma unroll
    for (int m = 0; m < 4; ++m)
        #pragma unroll
        for (int n = 0; n < 4; ++n)
            #pragma unroll
            for (int j = 0; j < 4; ++j) {
                int row = row0 + wr * 64 + m * 16 + (lane >> 4) * 4 + j;
                int col = n0 + wc * 64 + n * 16 + (lane & 15);
                float h = sw * acc[m][n][j];
                float r = fmaxf(h, 0.f) / s1v;
                float qv = fminf(rintf(r), 15.f);
                A1[(size_t)row * 512 + col] = (f16)qv;
                float fr = r - floorf(r);
                if (fabsf(fr - 0.5f) < FLAG_TOL) {
                    int p = atomicAdd(flagCnt, 1);
                    if (p < FLAG_CAP) flagList[p] = (unsigned)(row * 512 + col);
                }
            }
}

// ---------------- fixups: BLAS-replicating sequential fp32 FMA ----------------

__global__ void k_fixup1(const float* __restrict__ X, const float* __restrict__ W1dq,
                         const float* __restrict__ s1p,
                         const int* __restrict__ flagCnt, const unsigned* __restrict__ flagList,
                         f16* __restrict__ A1)
{
    int tid = blockIdx.x * blockDim.x + threadIdx.x;
    int nthr = gridDim.x * blockDim.x;
    int n = flagCnt[0];
    if (n > FLAG_CAP) n = FLAG_CAP;
    float s1 = s1p[0];
    for (int i = tid; i < n; i += nthr) {
        unsigned idx = flagList[i];
        int row = (int)(idx >> 9), col = (int)(idx & 511);
        const float* xr = X + (size_t)row * 784;
        const float* wr = W1dq + (size_t)col * 784;
        float acc = 0.f;
        for (int k = 0; k < 784; ++k)
            acc = fmaf(xr[k], wr[k], acc);
        float tq = fmaxf(acc, 0.f) / s1;
        float code = fminf(rintf(tq), 15.f);
        A1[(size_t)row * 512 + col] = (f16)code;
    }
}

__global__ void k_fixup2(const f16* __restrict__ A1, const float* __restrict__ W2dq,
                         const float* __restrict__ s1p, const float* __restrict__ s2p,
                         const int* __restrict__ flagCnt, const unsigned* __restrict__ flagList,
                         f16* __restrict__ A2)
{
    int tid = blockIdx.x * blockDim.x + threadIdx.x;
    int nthr = gridDim.x * blockDim.x;
    int n = flagCnt[0];
    if (n > FLAG_CAP) n = FLAG_CAP;
    float s1 = s1p[0], s2 = s2p[0];
    for (int i = tid; i < n; i += nthr) {
        unsigned idx = flagList[i];
        int row = (int)(idx >> 9), col = (int)(idx & 511);
        const f16* ar = A1 + (size_t)row * 512;
        const float* wr = W2dq + (size_t)col * 512;
        float acc = 0.f;
        for (int k = 0; k < 512; ++k) {
            float adq = (float)ar[k] * s1;
            acc = fmaf(adq, wr[k], acc);
        }
        float tq = fmaxf(acc, 0.f) / s2;
        float code = fminf(rintf(tq), 15.f);
        A2[(size_t)row * 512 + col] = (f16)code;
    }
}

// ---------------- GEMM3: [65536,512] @ [16,512]^T -> fp32 logits ----------------

__global__ __launch_bounds__(256) void k_gemm3(
    const f16* __restrict__ A2, const f16* __restrict__ Q3,
    const float* __restrict__ wmax, const float* __restrict__ s2p,
    float* __restrict__ Out)
{
    __shared__ __align__(16) f16 As[256][72];
    __shared__ __align__(16) f16 Bs[16][72];

    const int t = threadIdx.x;
    const int row0 = blockIdx.x * 256;
    const int lane = t & 63, wv = t >> 6;

    f32x4 acc[4];
    #pragma unroll
    for (int m = 0; m < 4; ++m) acc[m] = (f32x4){0.f, 0.f, 0.f, 0.f};

    for (int k0 = 0; k0 < 512; k0 += 64) {
        #pragma unroll
        for (int i = 0; i < 8; ++i) {
            int f = t + 256 * i;
            int r = f >> 3, c = f & 7;
            *reinterpret_cast<uint4*>(&As[r][c * 8]) =
                *reinterpret_cast<const uint4*>(A2 + (size_t)(row0 + r) * 512 + k0 + c * 8);
        }
        if (t < 128) {
            int r = t >> 3, c = t & 7;
            *reinterpret_cast<uint4*>(&Bs[r][c * 8]) =
                *reinterpret_cast<const uint4*>(Q3 + (size_t)r * 512 + k0 + c * 8);
        }
        __syncthreads();

        #pragma unroll
        for (int kk = 0; kk < 2; ++kk) {
            int kb = kk * 32 + (lane >> 4) * 8;
            f16x8 bf = *reinterpret_cast<const f16x8*>(&Bs[lane & 15][kb]);
            #pragma unroll
            for (int m = 0; m < 4; ++m) {
                f16x8 af = *reinterpret_cast<const f16x8*>(&As[wv * 64 + m * 16 + (lane & 15)][kb]);
                acc[m] = MFMA16(af, bf, acc[m]);
            }
        }
        __syncthreads();
    }

    double cs = (double)s2p[0] * (double)(wmax[0] / 7.0f + 1e-8f);
    #pragma unroll
    for (int m = 0; m < 4; ++m)
        #pragma unroll
        for (int j = 0; j < 4; ++j) {
            int row = row0 + wv * 64 + m * 16 + (lane >> 4) * 4 + j;
            int col = lane & 15;
            if (col < 10)
                Out[(size_t)row * 10 + col] = (float)((double)acc[m][j] * cs);
        }
}

// ---------------- launch ----------------

extern "C" void kernel_launch(void* const* d_in, const int* in_sizes, int n_in,
                              void* d_out, int out_size, void* d_ws, size_t ws_size,
                              hipStream_t stream)
{
    (void)in_sizes; (void)n_in; (void)out_size;

    const float* X  = (const float*)d_in[0];
    const float* W1 = (const float*)d_in[1];
    const float* W2 = (const float*)d_in[2];
    const float* W3 = (const float*)d_in[3];
    const float* s1 = (const float*)d_in[4];
    const float* s2 = (const float*)d_in[5];
    float* Out = (float*)d_out;

    char* ws = (char*)d_ws;
    float* maxes   = (float*)ws;
    int*   cnts    = (int*)(ws + 16);
    f16*   q1      = (f16*)(ws + 4096);                           // 802816 B
    f16*   q2      = (f16*)(ws + (size_t)(1u << 20));             // 524288 B
    f16*   q3      = (f16*)(ws + (size_t)(1u << 20) + 600000);    // 16384 B
    f16*   q1p     = (f16*)(ws + (size_t)(2u << 20));             // 1703936 B
    float* w1dq    = (float*)(ws + (size_t)(4u << 20));           // 1605632 B
    float* w2dq    = (float*)(ws + (size_t)(6u << 20));           // 1048576 B
    f16*   a1      = (f16*)(ws + (size_t)(8u << 20));             // 64 MB
    f16*   a2      = (f16*)(ws + (size_t)(72u << 20));            // 64 MB
    unsigned* fl1  = (unsigned*)(ws + (size_t)(136u << 20));      // 4 MB
    unsigned* fl2  = (unsigned*)(ws + (size_t)(140u << 20));      // 4 MB
    f16*   Xs      = (f16*)(ws + (size_t)(144u << 20));           // 218 MB (fast path)

    const bool big = ws_size >= ((size_t)356 << 20);

    k_zero<<<1, 64, 0, stream>>>(maxes, cnts);
    k_absmax<<<256, 256, 0, stream>>>(W1, 512 * 784, maxes + 0);
    k_absmax<<<256, 256, 0, stream>>>(W2, 512 * 512, maxes + 1);
    k_absmax<<<8, 256, 0, stream>>>(W3, 10 * 512, maxes + 2);
    k_quantw1p<<<(512 * 832 + 255) / 256, 256, 0, stream>>>(W1, maxes + 0, q1, w1dq, q1p);
    k_quantw<<<(512 * 512 + 255) / 256, 256, 0, stream>>>(W2, maxes + 1, q2, w2dq, 512 * 512);
    k_quantw3<<<(16 * 512 + 255) / 256, 256, 0, stream>>>(W3, maxes + 2, q3);

    if (big) {
        k_prep<<<65536, 256, 0, stream>>>(X, Xs);
        k_gemm1p<<<2048, 256, 0, stream>>>(Xs, q1p, maxes + 0, s1, a1, cnts + 0, fl1);
    } else {
        k_gemm1s<<<dim3(4, 512), 256, 0, stream>>>(X, q1, maxes + 0, s1, a1, cnts + 0, fl1);
    }
    k_fixup1<<<512, 256, 0, stream>>>(X, w1dq, s1, cnts + 0, fl1, a1);
    k_gemm2p<<<2048, 256, 0, stream>>>(a1, q2, maxes + 1, s1, s2, a2, cnts + 1, fl2);
    k_fixup2<<<512, 256, 0, stream>>>(a1, w2dq, s1, s2, cnts + 1, fl2, a2);
    k_gemm3<<<256, 256, 0, stream>>>(a2, q3, maxes + 2, s2, Out);
}

// Round 9
// 669.475 us; speedup vs baseline: 1.2607x; 1.1282x over previous
//
#include <hip/hip_runtime.h>
#include <hip/hip_fp16.h>

typedef _Float16 f16;
typedef _Float16 f16x4 __attribute__((ext_vector_type(4)));
typedef _Float16 f16x8 __attribute__((ext_vector_type(8)));
typedef float f32x4 __attribute__((ext_vector_type(4)));
typedef int i32x4 __attribute__((ext_vector_type(4)));

#define MFMA16(a, b, c) __builtin_amdgcn_mfma_f32_16x16x32_f16((a), (b), (c), 0, 0, 0)
#define MFMAI8(a, b, c) __builtin_amdgcn_mfma_i32_16x16x64_i8((a), (b), (c), 0, 0, 0)

#define FLAG_CAP (1024 * 1024)
#define FLAG_TOL 1e-3f

// async global->LDS, 16 B per lane. LDS dest is wave-uniform base (+lane*16);
// global src is per-lane (swizzle baked into source address).
__device__ __forceinline__ void gld16(const void* g, void* l) {
    __builtin_amdgcn_global_load_lds(
        (const __attribute__((address_space(1))) unsigned int*)g,
        (__attribute__((address_space(3))) unsigned int*)l,
        16, 0, 0);
}

// ---------------- scale computation ----------------

__global__ void k_zero(float* p, int* cnt) {
    if (threadIdx.x < 3) p[threadIdx.x] = 0.f;
    if (threadIdx.x == 3) { cnt[0] = 0; cnt[1] = 0; }
}

__global__ void k_absmax(const float* __restrict__ w, int n, float* __restrict__ out) {
    float m = 0.f;
    int stride = gridDim.x * blockDim.x;
    for (int i = blockIdx.x * blockDim.x + threadIdx.x; i < n; i += stride)
        m = fmaxf(m, fabsf(w[i]));
    #pragma unroll
    for (int o = 32; o > 0; o >>= 1) m = fmaxf(m, __shfl_down(m, o));
    __shared__ float sm[4];
    int lane = threadIdx.x & 63, wv = threadIdx.x >> 6;
    if (lane == 0) sm[wv] = m;
    __syncthreads();
    if (threadIdx.x == 0) {
        float mm = fmaxf(fmaxf(sm[0], sm[1]), fmaxf(sm[2], sm[3]));
        atomicMax((unsigned int*)out, __float_as_uint(mm));  // nonneg floats only
    }
}

// W1: compact q1 f16 (fallback), fp32 dequant w1dq (fixup), single padded
// B panel q1h [512][832] f16. fp32 ops replicate numpy semantics.
__global__ void k_quantw1(const float* __restrict__ w, const float* __restrict__ wmax,
                          f16* __restrict__ q1, float* __restrict__ wdq,
                          f16* __restrict__ q1h) {
    int i = blockIdx.x * blockDim.x + threadIdx.x;
    if (i >= 512 * 832) return;
    int n = i / 832, k = i - n * 832;
    float v = 0.f;
    if (k < 784) {
        float s = wmax[0] / 7.0f + 1e-8f;
        v = rintf(w[n * 784 + k] / s);
        v = fminf(fmaxf(v, -7.f), 7.f);
        q1[n * 784 + k] = (f16)v;
        wdq[n * 784 + k] = v * s;
    }
    q1h[(size_t)n * 832 + k] = (f16)v;
}

// W2: int8 codes + fp32 dequant (fixup)
__global__ void k_quantw2(const float* __restrict__ w, const float* __restrict__ wmax,
                          signed char* __restrict__ q, float* __restrict__ wdq, int n) {
    float s = wmax[0] / 7.0f + 1e-8f;
    int i = blockIdx.x * blockDim.x + threadIdx.x;
    if (i < n) {
        float v = rintf(w[i] / s);
        v = fminf(fmaxf(v, -7.f), 7.f);
        q[i] = (signed char)v;
        if (wdq) wdq[i] = v * s;
    }
}

// W3: int8, zero-padded to 16x512
__global__ void k_quantw3(const float* __restrict__ w, const float* __restrict__ wmax,
                          signed char* __restrict__ q) {
    float s = wmax[0] / 7.0f + 1e-8f;
    int i = blockIdx.x * blockDim.x + threadIdx.x;
    if (i < 16 * 512) {
        float v = 0.f;
        if (i < 10 * 512) {
            v = rintf(w[i] / s);
            v = fminf(fmaxf(v, -7.f), 7.f);
        }
        q[i] = (signed char)v;
    }
}

// ---------------- prep: split X fp32 -> [hi(832) | lo(832)] f16, zero-padded ----------------

__global__ void k_prep(const float* __restrict__ X, f16* __restrict__ Xs) {
    int row = blockIdx.x;
    int p = threadIdx.x;
    if (p >= 208) return;
    f16x4 h0 = (f16x4){0, 0, 0, 0}, h1 = (f16x4){0, 0, 0, 0};
    if (p < 196) {
        float4 v = *reinterpret_cast<const float4*>(X + (size_t)row * 784 + p * 4);
        float vv[4] = {v.x, v.y, v.z, v.w};
        #pragma unroll
        for (int j = 0; j < 4; ++j) {
            f16 c0 = (f16)vv[j];                 // RNE
            h0[j] = c0;
            h1[j] = (f16)(vv[j] - (float)c0);    // exact residual
        }
    }
    *reinterpret_cast<f16x4*>(Xs + (size_t)row * 1664 + p * 4) = h0;
    *reinterpret_cast<f16x4*>(Xs + (size_t)row * 1664 + 832 + p * 4) = h1;
}

// ========== GEMM1: K=832 pair-tiles, 3 LDS tiles (Ah, Al, B staged ONCE) ==========
// m97 rhythm (stage -> sync -> compute -> sync). LDS element (r,c) at
// r*64 + (c ^ ((r&7)<<3)); write-side swizzle via global source column.

__global__ __launch_bounds__(256, 3) void k_gemm1h(
    const f16* __restrict__ A, const f16* __restrict__ B,
    const float* __restrict__ wmax, const float* __restrict__ s1p,
    signed char* __restrict__ A1, int* __restrict__ flagCnt, unsigned* __restrict__ flagList)
{
    constexpr int KA = 1664;   // Xs row stride (hi | lo)
    constexpr int KB = 832;    // q1h row stride
    constexpr int NT = 13;     // 832/64
    __shared__ __align__(16) f16 Ah[128 * 64];
    __shared__ __align__(16) f16 Al[128 * 64];
    __shared__ __align__(16) f16 Bt[128 * 64];

    const int t = threadIdx.x;
    const int lane = t & 63, w = t >> 6;
    const int wr = w >> 1, wc = w & 1;

    const int bid = blockIdx.x;
    const int lg = (bid & 7) * 256 + (bid >> 3);
    const int n0 = (lg & 3) * 128;
    const int row0 = (lg >> 2) * 128;

    f32x4 acc[4][4];
    #pragma unroll
    for (int m = 0; m < 4; ++m)
        #pragma unroll
        for (int n = 0; n < 4; ++n) acc[m][n] = (f32x4){0.f, 0.f, 0.f, 0.f};

    const int lr = lane >> 3;                          // row within 8-row chunk
    const int lc = (((lane & 7) ^ (lane >> 3)) * 8);   // swizzled col (f16 units)
    const f16* Ahb = A + (size_t)(row0 + lr) * KA + lc;
    const f16* Alb = A + (size_t)(row0 + lr) * KA + 832 + lc;
    const f16* Bb  = B + (size_t)(n0 + lr) * KB + lc;

    for (int tt = 0; tt < NT; ++tt) {
        const int k0 = tt * 64;
        #pragma unroll
        for (int i = 0; i < 4; ++i) {
            int ch = w * 4 + i;                        // 16 chunks x 8 rows
            gld16(Ahb + (size_t)ch * 8 * KA + k0, &Ah[ch * 512]);
            gld16(Alb + (size_t)ch * 8 * KA + k0, &Al[ch * 512]);
            gld16(Bb  + (size_t)ch * 8 * KB + k0, &Bt[ch * 512]);
        }
        __syncthreads();

        #pragma unroll
        for (int kk = 0; kk < 2; ++kk) {
            int kb = kk * 32 + (lane >> 4) * 8;
            int ksw = kb ^ ((lane & 7) << 3);
            f16x8 bf[4], fh[4], fl[4];
            #pragma unroll
            for (int n = 0; n < 4; ++n)
                bf[n] = *reinterpret_cast<const f16x8*>(&Bt[(wc * 64 + n * 16 + (lane & 15)) * 64 + ksw]);
            #pragma unroll
            for (int m = 0; m < 4; ++m) {
                fh[m] = *reinterpret_cast<const f16x8*>(&Ah[(wr * 64 + m * 16 + (lane & 15)) * 64 + ksw]);
                fl[m] = *reinterpret_cast<const f16x8*>(&Al[(wr * 64 + m * 16 + (lane & 15)) * 64 + ksw]);
            }
            #pragma unroll
            for (int m = 0; m < 4; ++m)
                #pragma unroll
                for (int n = 0; n < 4; ++n) {
                    acc[m][n] = MFMA16(fh[m], bf[n], acc[m][n]);
                    acc[m][n] = MFMA16(fl[m], bf[n], acc[m][n]);
                }
        }
        __syncthreads();
    }

    float sw = wmax[0] / 7.0f + 1e-8f;
    float s1v = s1p[0];
    #pragma unroll
    for (int m = 0; m < 4; ++m)
        #pragma unroll
        for (int n = 0; n < 4; ++n)
            #pragma unroll
            for (int j = 0; j < 4; ++j) {
                int row = row0 + wr * 64 + m * 16 + (lane >> 4) * 4 + j;
                int col = n0 + wc * 64 + n * 16 + (lane & 15);
                float h = sw * acc[m][n][j];
                float r = fmaxf(h, 0.f) / s1v;
                float qv = fminf(rintf(r), 15.f);
                A1[(size_t)row * 512 + col] = (signed char)qv;
                float fr = r - floorf(r);
                if (fabsf(fr - 0.5f) < FLAG_TOL) {
                    int p = atomicAdd(flagCnt, 1);
                    if (p < FLAG_CAP) flagList[p] = (unsigned)(row * 512 + col);
                }
            }
}

// ========== GEMM2: int8 exact dot (same 128-byte-row geometry as f16 version) ==========
// K=512 i8, BK=128 bytes/tile, 4 tiles. Rows are 128 B -> identical swizzle
// constants to the f16 kernel. mfma_i32_16x16x64_i8, fp64 epilogue.

__global__ __launch_bounds__(256, 4) void k_gemm2i(
    const signed char* __restrict__ A, const signed char* __restrict__ B,
    const float* __restrict__ wmax, const float* __restrict__ s1p, const float* __restrict__ s2p,
    signed char* __restrict__ A2, int* __restrict__ flagCnt, unsigned* __restrict__ flagList)
{
    constexpr int KP = 512;                  // bytes per row
    constexpr int NT = 4;                    // 4 tiles x 128 B
    __shared__ __align__(16) signed char As[128 * 128];
    __shared__ __align__(16) signed char Bs[128 * 128];

    const int t = threadIdx.x;
    const int lane = t & 63, w = t >> 6;
    const int wr = w >> 1, wc = w & 1;

    const int bid = blockIdx.x;
    const int lg = (bid & 7) * 256 + (bid >> 3);
    const int n0 = (lg & 3) * 128;
    const int row0 = (lg >> 2) * 128;

    i32x4 acc[4][4];
    #pragma unroll
    for (int m = 0; m < 4; ++m)
        #pragma unroll
        for (int n = 0; n < 4; ++n) acc[m][n] = (i32x4){0, 0, 0, 0};

    const int lr = lane >> 3;                           // row within 8-row chunk
    const int lcb = (((lane & 7) ^ (lane >> 3)) * 16);  // swizzled byte col
    const signed char* Ab = A + (size_t)(row0 + lr) * KP + lcb;
    const signed char* Bb = B + (size_t)(n0 + lr) * KP + lcb;

    for (int tt = 0; tt < NT; ++tt) {
        const int k0 = tt * 128;                        // byte offset
        #pragma unroll
        for (int i = 0; i < 4; ++i) {
            int ch = w * 4 + i;                         // 16 chunks x 8 rows
            gld16(Ab + (size_t)ch * 8 * KP + k0, &As[ch * 1024]);
            gld16(Bb + (size_t)ch * 8 * KP + k0, &Bs[ch * 1024]);
        }
        __syncthreads();

        #pragma unroll
        for (int kk = 0; kk < 2; ++kk) {
            int sl = kk * 4 + (lane >> 4);              // 16B slot 0..7
            int slw = (sl ^ (lane & 7)) * 16;           // read-side swizzle
            i32x4 bf[4], af[4];
            #pragma unroll
            for (int n = 0; n < 4; ++n)
                bf[n] = *reinterpret_cast<const i32x4*>(&Bs[(wc * 64 + n * 16 + (lane & 15)) * 128 + slw]);
            #pragma unroll
            for (int m = 0; m < 4; ++m)
                af[m] = *reinterpret_cast<const i32x4*>(&As[(wr * 64 + m * 16 + (lane & 15)) * 128 + slw]);
            #pragma unroll
            for (int m = 0; m < 4; ++m)
                #pragma unroll
                for (int n = 0; n < 4; ++n)
                    acc[m][n] = MFMAI8(af[m], bf[n], acc[m][n]);
        }
        __syncthreads();
    }

    double cs = (double)s1p[0] * (double)(wmax[0] / 7.0f + 1e-8f);
    double s2v = (double)s2p[0];
    #pragma unroll
    for (int m = 0; m < 4; ++m)
        #pragma unroll
        for (int n = 0; n < 4; ++n)
            #pragma unroll
            for (int j = 0; j < 4; ++j) {
                int row = row0 + wr * 64 + m * 16 + (lane >> 4) * 4 + j;
                int col = n0 + wc * 64 + n * 16 + (lane & 15);
                double r = fmax((double)acc[m][n][j] * cs, 0.0) / s2v;
                double qv = fmin(rint(r), 15.0);
                A2[(size_t)row * 512 + col] = (signed char)qv;
                double fr = r - floor(r);
                if (fabs(fr - 0.5) < (double)FLAG_TOL && r < 16.0) {
                    int p = atomicAdd(flagCnt, 1);
                    if (p < FLAG_CAP) flagList[p] = (unsigned)(row * 512 + col);
                }
            }
}

// ---------------- fallback GEMM1 (round-3 style, in-kernel split, i8 out) ----------------

__global__ __launch_bounds__(256) void k_gemm1s(
    const float* __restrict__ X, const f16* __restrict__ Q1,
    const float* __restrict__ wmax, const float* __restrict__ s1p,
    signed char* __restrict__ A1, int* __restrict__ flagCnt, unsigned* __restrict__ flagList)
{
    __shared__ __align__(16) f16 As0[128][72];
    __shared__ __align__(16) f16 As1[128][72];
    __shared__ __align__(16) f16 Bs[128][72];

    const int t = threadIdx.x;
    const int row0 = blockIdx.y * 128;
    const int n0 = blockIdx.x * 128;
    const int lane = t & 63, wv = t >> 6;
    const int wr = wv >> 1, wc = wv & 1;

    f32x4 acc[4][4];
    #pragma unroll
    for (int m = 0; m < 4; ++m)
        #pragma unroll
        for (int n = 0; n < 4; ++n) acc[m][n] = (f32x4){0.f, 0.f, 0.f, 0.f};

    for (int k0 = 0; k0 < 784; k0 += 64) {
        #pragma unroll
        for (int i = 0; i < 8; ++i) {
            int f = t + 256 * i;
            int r = f >> 4, c = f & 15;
            int gk = k0 + c * 4;
            float4 v = make_float4(0.f, 0.f, 0.f, 0.f);
            if (gk < 784)
                v = *reinterpret_cast<const float4*>(X + (size_t)(row0 + r) * 784 + gk);
            float vv[4] = {v.x, v.y, v.z, v.w};
            f16x4 h0, h1;
            #pragma unroll
            for (int j = 0; j < 4; ++j) {
                f16 c0 = (f16)vv[j];
                h0[j] = c0;
                h1[j] = (f16)(vv[j] - (float)c0);
            }
            *reinterpret_cast<f16x4*>(&As0[r][c * 4]) = h0;
            *reinterpret_cast<f16x4*>(&As1[r][c * 4]) = h1;
        }
        #pragma unroll
        for (int i = 0; i < 4; ++i) {
            int f = t + 256 * i;
            int r = f >> 3, c = f & 7;
            int gk = k0 + c * 8;
            uint4 u = make_uint4(0u, 0u, 0u, 0u);
            if (gk < 784)
                u = *reinterpret_cast<const uint4*>(Q1 + (size_t)(n0 + r) * 784 + gk);
            *reinterpret_cast<uint4*>(&Bs[r][c * 8]) = u;
        }
        __syncthreads();

        #pragma unroll
        for (int kk = 0; kk < 2; ++kk) {
            int kb = kk * 32 + (lane >> 4) * 8;
            f16x8 bf[4], a0[4], a1f[4];
            #pragma unroll
            for (int n = 0; n < 4; ++n)
                bf[n] = *reinterpret_cast<const f16x8*>(&Bs[wc * 64 + n * 16 + (lane & 15)][kb]);
            #pragma unroll
            for (int m = 0; m < 4; ++m) {
                a0[m]  = *reinterpret_cast<const f16x8*>(&As0[wr * 64 + m * 16 + (lane & 15)][kb]);
                a1f[m] = *reinterpret_cast<const f16x8*>(&As1[wr * 64 + m * 16 + (lane & 15)][kb]);
            }
            #pragma unroll
            for (int m = 0; m < 4; ++m)
                #pragma unroll
                for (int n = 0; n < 4; ++n) {
                    acc[m][n] = MFMA16(a0[m],  bf[n], acc[m][n]);
                    acc[m][n] = MFMA16(a1f[m], bf[n], acc[m][n]);
                }
        }
        __syncthreads();
    }

    float sw = wmax[0] / 7.0f + 1e-8f;
    float s1v = s1p[0];
    #pragma unroll
    for (int m = 0; m < 4; ++m)
        #pragma unroll
        for (int n = 0; n < 4; ++n)
            #pragma unroll
            for (int j = 0; j < 4; ++j) {
                int row = row0 + wr * 64 + m * 16 + (lane >> 4) * 4 + j;
                int col = n0 + wc * 64 + n * 16 + (lane & 15);
                float h = sw * acc[m][n][j];
                float r = fmaxf(h, 0.f) / s1v;
                float qv = fminf(rintf(r), 15.f);
                A1[(size_t)row * 512 + col] = (signed char)qv;
                float fr = r - floorf(r);
                if (fabsf(fr - 0.5f) < FLAG_TOL) {
                    int p = atomicAdd(flagCnt, 1);
                    if (p < FLAG_CAP) flagList[p] = (unsigned)(row * 512 + col);
                }
            }
}

// ---------------- fixups: BLAS-replicating sequential fp32 FMA ----------------

__global__ void k_fixup1(const float* __restrict__ X, const float* __restrict__ W1dq,
                         const float* __restrict__ s1p,
                         const int* __restrict__ flagCnt, const unsigned* __restrict__ flagList,
                         signed char* __restrict__ A1)
{
    int tid = blockIdx.x * blockDim.x + threadIdx.x;
    int nthr = gridDim.x * blockDim.x;
    int n = flagCnt[0];
    if (n > FLAG_CAP) n = FLAG_CAP;
    float s1 = s1p[0];
    for (int i = tid; i < n; i += nthr) {
        unsigned idx = flagList[i];
        int row = (int)(idx >> 9), col = (int)(idx & 511);
        const float* xr = X + (size_t)row * 784;
        const float* wr = W1dq + (size_t)col * 784;
        float acc = 0.f;
        for (int k = 0; k < 784; ++k)
            acc = fmaf(xr[k], wr[k], acc);       // k-ascending, single acc: BLAS order
        float tq = fmaxf(acc, 0.f) / s1;
        float code = fminf(rintf(tq), 15.f);
        A1[(size_t)row * 512 + col] = (signed char)code;
    }
}

__global__ void k_fixup2(const signed char* __restrict__ A1, const float* __restrict__ W2dq,
                         const float* __restrict__ s1p, const float* __restrict__ s2p,
                         const int* __restrict__ flagCnt, const unsigned* __restrict__ flagList,
                         signed char* __restrict__ A2)
{
    int tid = blockIdx.x * blockDim.x + threadIdx.x;
    int nthr = gridDim.x * blockDim.x;
    int n = flagCnt[0];
    if (n > FLAG_CAP) n = FLAG_CAP;
    float s1 = s1p[0], s2 = s2p[0];
    for (int i = tid; i < n; i += nthr) {
        unsigned idx = flagList[i];
        int row = (int)(idx >> 9), col = (int)(idx & 511);
        const signed char* ar = A1 + (size_t)row * 512;
        const float* wr = W2dq + (size_t)col * 512;
        float acc = 0.f;
        for (int k = 0; k < 512; ++k) {
            float adq = (float)ar[k] * s1;       // fp32 dequant, == ref
            acc = fmaf(adq, wr[k], acc);
        }
        float tq = fmaxf(acc, 0.f) / s2;
        float code = fminf(rintf(tq), 15.f);
        A2[(size_t)row * 512 + col] = (signed char)code;
    }
}

// ---------------- GEMM3: int8 [65536,512] @ [16,512]^T -> fp32 logits ----------------

__global__ __launch_bounds__(256) void k_gemm3i(
    const signed char* __restrict__ A2, const signed char* __restrict__ Q3,
    const float* __restrict__ wmax, const float* __restrict__ s2p,
    float* __restrict__ Out)
{
    __shared__ __align__(16) signed char As[256][80];   // 64B data + 16B pad
    __shared__ __align__(16) signed char Bs[16][80];

    const int t = threadIdx.x;
    const int row0 = blockIdx.x * 256;
    const int lane = t & 63, wv = t >> 6;

    i32x4 acc[4];
    #pragma unroll
    for (int m = 0; m < 4; ++m) acc[m] = (i32x4){0, 0, 0, 0};

    for (int k0 = 0; k0 < 512; k0 += 64) {
        #pragma unroll
        for (int i = 0; i < 4; ++i) {
            int f = t + 256 * i;
            int r = f >> 2, c = f & 3;
            *reinterpret_cast<uint4*>(&As[r][c * 16]) =
                *reinterpret_cast<const uint4*>(A2 + (size_t)(row0 + r) * 512 + k0 + c * 16);
        }
        if (t < 64) {
            int r = t >> 2, c = t & 3;
            *reinterpret_cast<uint4*>(&Bs[r][c * 16]) =
                *reinterpret_cast<const uint4*>(Q3 + (size_t)r * 512 + k0 + c * 16);
        }
        __syncthreads();

        i32x4 bf = *reinterpret_cast<const i32x4*>(&Bs[lane & 15][(lane >> 4) * 16]);
        #pragma unroll
        for (int m = 0; m < 4; ++m) {
            i32x4 af = *reinterpret_cast<const i32x4*>(&As[wv * 64 + m * 16 + (lane & 15)][(lane >> 4) * 16]);
            acc[m] = MFMAI8(af, bf, acc[m]);
        }
        __syncthreads();
    }

    double cs = (double)s2p[0] * (double)(wmax[0] / 7.0f + 1e-8f);
    #pragma unroll
    for (int m = 0; m < 4; ++m)
        #pragma unroll
        for (int j = 0; j < 4; ++j) {
            int row = row0 + wv * 64 + m * 16 + (lane >> 4) * 4 + j;
            int col = lane & 15;
            if (col < 10)
                Out[(size_t)row * 10 + col] = (float)((double)acc[m][j] * cs);
        }
}

// ---------------- launch ----------------

extern "C" void kernel_launch(void* const* d_in, const int* in_sizes, int n_in,
                              void* d_out, int out_size, void* d_ws, size_t ws_size,
                              hipStream_t stream)
{
    (void)in_sizes; (void)n_in; (void)out_size;

    const float* X  = (const float*)d_in[0];
    const float* W1 = (const float*)d_in[1];
    const float* W2 = (const float*)d_in[2];
    const float* W3 = (const float*)d_in[3];
    const float* s1 = (const float*)d_in[4];
    const float* s2 = (const float*)d_in[5];
    float* Out = (float*)d_out;

    char* ws = (char*)d_ws;
    float* maxes        = (float*)ws;
    int*   cnts         = (int*)(ws + 16);
    f16*   q1           = (f16*)(ws + 4096);                         // 802816 B (fallback)
    signed char* q2i    = (signed char*)(ws + (size_t)(1u << 20));   // 262144 B
    signed char* q3i    = (signed char*)(ws + (size_t)(1u << 20) + 300000);  // 8192 B
    f16*   q1h          = (f16*)(ws + (size_t)(2u << 20));           // 851968 B
    float* w1dq         = (float*)(ws + (size_t)(4u << 20));         // 1605632 B
    float* w2dq         = (float*)(ws + (size_t)(6u << 20));         // 1048576 B
    signed char* a1     = (signed char*)(ws + (size_t)(8u << 20));   // 32 MB
    signed char* a2     = (signed char*)(ws + (size_t)(40u << 20));  // 32 MB
    unsigned* fl1       = (unsigned*)(ws + (size_t)(72u << 20));     // 4 MB
    unsigned* fl2       = (unsigned*)(ws + (size_t)(76u << 20));     // 4 MB
    f16*   Xs           = (f16*)(ws + (size_t)(80u << 20));          // 218 MB (fast path)

    const bool big = ws_size >= ((size_t)300 << 20);

    k_zero<<<1, 64, 0, stream>>>(maxes, cnts);
    k_absmax<<<256, 256, 0, stream>>>(W1, 512 * 784, maxes + 0);
    k_absmax<<<256, 256, 0, stream>>>(W2, 512 * 512, maxes + 1);
    k_absmax<<<8, 256, 0, stream>>>(W3, 10 * 512, maxes + 2);
    k_quantw1<<<(512 * 832 + 255) / 256, 256, 0, stream>>>(W1, maxes + 0, q1, w1dq, q1h);
    k_quantw2<<<(512 * 512 + 255) / 256, 256, 0, stream>>>(W2, maxes + 1, q2i, w2dq, 512 * 512);
    k_quantw3<<<(16 * 512 + 255) / 256, 256, 0, stream>>>(W3, maxes + 2, q3i);

    if (big) {
        k_prep<<<65536, 256, 0, stream>>>(X, Xs);
        k_gemm1h<<<2048, 256, 0, stream>>>(Xs, q1h, maxes + 0, s1, a1, cnts + 0, fl1);
    } else {
        k_gemm1s<<<dim3(4, 512), 256, 0, stream>>>(X, q1, maxes + 0, s1, a1, cnts + 0, fl1);
    }
    k_fixup1<<<512, 256, 0, stream>>>(X, w1dq, s1, cnts + 0, fl1, a1);
    k_gemm2i<<<2048, 256, 0, stream>>>(a1, q2i, maxes + 1, s1, s2, a2, cnts + 1, fl2);
    k_fixup2<<<512, 256, 0, stream>>>(a1, w2dq, s1, s2, cnts + 1, fl2, a2);
    k_gemm3i<<<256, 256, 0, stream>>>(a2, q3i, maxes + 2, s2, Out);
}

// Round 10
// 624.365 us; speedup vs baseline: 1.3518x; 1.0722x over previous
//
#include <hip/hip_runtime.h>
#include <hip/hip_fp16.h>

typedef _Float16 f16;
typedef _Float16 f16x4 __attribute__((ext_vector_type(4)));
typedef _Float16 f16x8 __attribute__((ext_vector_type(8)));
typedef float f32x4 __attribute__((ext_vector_type(4)));
typedef int i32x4 __attribute__((ext_vector_type(4)));

#define MFMA16(a, b, c) __builtin_amdgcn_mfma_f32_16x16x32_f16((a), (b), (c), 0, 0, 0)
#define MFMAI8(a, b, c) __builtin_amdgcn_mfma_i32_16x16x64_i8((a), (b), (c), 0, 0, 0)

#define FLAG_CAP (1024 * 1024)
#define FLAG_TOL 1e-3f

#define SBAR()   __builtin_amdgcn_s_barrier()
#define SCHEDB() __builtin_amdgcn_sched_barrier(0)

// async global->LDS, 16 B per lane. LDS dest is wave-uniform base (+lane*16);
// global src is per-lane (swizzle baked into source address).
__device__ __forceinline__ void gld16(const void* g, void* l) {
    __builtin_amdgcn_global_load_lds(
        (const __attribute__((address_space(1))) unsigned int*)g,
        (__attribute__((address_space(3))) unsigned int*)l,
        16, 0, 0);
}

// ---------------- scale computation ----------------

__global__ void k_zero(float* p, int* cnt) {
    if (threadIdx.x < 3) p[threadIdx.x] = 0.f;
    if (threadIdx.x == 3) { cnt[0] = 0; cnt[1] = 0; }
}

__global__ void k_absmax(const float* __restrict__ w, int n, float* __restrict__ out) {
    float m = 0.f;
    int stride = gridDim.x * blockDim.x;
    for (int i = blockIdx.x * blockDim.x + threadIdx.x; i < n; i += stride)
        m = fmaxf(m, fabsf(w[i]));
    #pragma unroll
    for (int o = 32; o > 0; o >>= 1) m = fmaxf(m, __shfl_down(m, o));
    __shared__ float sm[4];
    int lane = threadIdx.x & 63, wv = threadIdx.x >> 6;
    if (lane == 0) sm[wv] = m;
    __syncthreads();
    if (threadIdx.x == 0) {
        float mm = fmaxf(fmaxf(sm[0], sm[1]), fmaxf(sm[2], sm[3]));
        atomicMax((unsigned int*)out, __float_as_uint(mm));  // nonneg floats only
    }
}

// W1: fp32 dequant w1dq (fixup) + padded f16 panel q1h [512][832]
__global__ void k_quantw1(const float* __restrict__ w, const float* __restrict__ wmax,
                          float* __restrict__ wdq, f16* __restrict__ q1h) {
    int i = blockIdx.x * blockDim.x + threadIdx.x;
    if (i >= 512 * 832) return;
    int n = i / 832, k = i - n * 832;
    float v = 0.f;
    if (k < 784) {
        float s = wmax[0] / 7.0f + 1e-8f;
        v = rintf(w[n * 784 + k] / s);       // fp32 ops replicate numpy semantics
        v = fminf(fmaxf(v, -7.f), 7.f);
        wdq[n * 784 + k] = v * s;
    }
    q1h[(size_t)n * 832 + k] = (f16)v;
}

// W2: int8 codes + fp32 dequant (fixup)
__global__ void k_quantw2(const float* __restrict__ w, const float* __restrict__ wmax,
                          signed char* __restrict__ q, float* __restrict__ wdq, int n) {
    float s = wmax[0] / 7.0f + 1e-8f;
    int i = blockIdx.x * blockDim.x + threadIdx.x;
    if (i < n) {
        float v = rintf(w[i] / s);
        v = fminf(fmaxf(v, -7.f), 7.f);
        q[i] = (signed char)v;
        if (wdq) wdq[i] = v * s;
    }
}

// W3: int8, zero-padded to 16x512
__global__ void k_quantw3(const float* __restrict__ w, const float* __restrict__ wmax,
                          signed char* __restrict__ q) {
    float s = wmax[0] / 7.0f + 1e-8f;
    int i = blockIdx.x * blockDim.x + threadIdx.x;
    if (i < 16 * 512) {
        float v = 0.f;
        if (i < 10 * 512) {
            v = rintf(w[i] / s);
            v = fminf(fmaxf(v, -7.f), 7.f);
        }
        q[i] = (signed char)v;
    }
}

// ========== GEMM1: fused full-N block (128 rows x 512 cols), K=832 ==========
// Reads X (fp32) directly; in-register hi/lo f16 split (T14 async staging);
// B (q1h, L2-hot) via gld16 single-buffered; A-LDS double-buffered.
// LDS element (r,c) at r*64 + (c ^ ((r&7)<<3)); A written swizzled by ds_write,
// B swizzled via pre-swizzled global source. 128 KB LDS, 1 block/CU, 8 waves.

__global__ __launch_bounds__(512, 2) void k_gemm1F(
    const float* __restrict__ X, const f16* __restrict__ B,
    const float* __restrict__ wmax, const float* __restrict__ s1p,
    signed char* __restrict__ A1, int* __restrict__ flagCnt, unsigned* __restrict__ flagList)
{
    constexpr int NT = 13;                   // 832/64 K-tiles
    __shared__ __align__(16) f16 Ah[2][128 * 64];   // 32 KB
    __shared__ __align__(16) f16 Al[2][128 * 64];   // 32 KB
    __shared__ __align__(16) f16 Bt[512 * 64];      // 64 KB

    const int t = threadIdx.x;
    const int lane = t & 63, w = t >> 6;
    const int wr = w >> 2, wc = w & 3;       // 2 x 4 wave grid, wave tile 64x128
    const int l15 = lane & 15, l4 = lane >> 4;
    const int row0 = blockIdx.x * 128;

    f32x4 acc[4][8];
    #pragma unroll
    for (int m = 0; m < 4; ++m)
        #pragma unroll
        for (int n = 0; n < 8; ++n) acc[m][n] = (f32x4){0.f, 0.f, 0.f, 0.f};

    // B staging: lane -> row lr within 8-row chunk, swizzled col slot
    const int lr = lane >> 3;
    const int lc = ((lane & 7) ^ lr) * 8;
    const f16* Bb = B + (size_t)lr * 832 + lc;

    float4 av[4];
    // A-tile reg load for tile tn (predicated zero-pad past col 784)
    auto LOADA = [&](int tn) {
        #pragma unroll
        for (int i = 0; i < 4; ++i) {
            int f = t + 512 * i;
            int r = f >> 4, s = f & 15;      // s = lane&15: every wave issues all 4
            int gk = tn * 64 + s * 4;
            av[i] = make_float4(0.f, 0.f, 0.f, 0.f);
            if (gk < 784)
                av[i] = *reinterpret_cast<const float4*>(X + (size_t)(row0 + r) * 784 + gk);
        }
    };
    // split av -> hi/lo f16, swizzled ds_write into buffer buf
    auto WRITEA = [&](int buf) {
        #pragma unroll
        for (int i = 0; i < 4; ++i) {
            int f = t + 512 * i;
            int r = f >> 4, s = f & 15;
            float vv[4] = {av[i].x, av[i].y, av[i].z, av[i].w};
            f16x4 h0, h1;
            #pragma unroll
            for (int j = 0; j < 4; ++j) {
                f16 c0 = (f16)vv[j];                 // RNE
                h0[j] = c0;
                h1[j] = (f16)(vv[j] - (float)c0);    // exact residual
            }
            int ad = r * 64 + ((s * 4) ^ ((r & 7) << 3));
            *reinterpret_cast<f16x4*>(&Ah[buf][ad]) = h0;
            *reinterpret_cast<f16x4*>(&Al[buf][ad]) = h1;
        }
    };

    // prologue: tile 0 into A-LDS[0]
    LOADA(0);
    asm volatile("s_waitcnt vmcnt(0)" ::: "memory");
    WRITEA(0);

    int cur = 0;
    for (int tt = 0; tt < NT; ++tt) {
        // stage B(tt) -- 8 gld16/wave
        #pragma unroll
        for (int i = 0; i < 8; ++i) {
            int ch = w * 8 + i;              // 64 chunks x 8 rows = 512 rows
            gld16(Bb + (size_t)ch * 8 * 832 + tt * 64, &Bt[ch * 512]);
        }
        SCHEDB();
        // prefetch A regs for next tile (clamped; redundant at tail, harmless)
        int tn = (tt + 1 < NT) ? tt + 1 : tt;
        LOADA(tn);
        SCHEDB();
        asm volatile("s_waitcnt vmcnt(4)" ::: "memory");   // B landed; A(4) still flying
        asm volatile("s_waitcnt lgkmcnt(0)" ::: "memory"); // my ds_writes drained
        SBAR();                                            // A-LDS[cur] + B ready for all

        #pragma unroll
        for (int kk = 0; kk < 2; ++kk) {
            int kb = kk * 32 + l4 * 8;
            int ksw = kb ^ ((lane & 7) << 3);
            f16x8 fh[4], fl_[4], bf[8];
            #pragma unroll
            for (int m = 0; m < 4; ++m) {
                fh[m]  = *reinterpret_cast<const f16x8*>(&Ah[cur][(wr * 64 + m * 16 + l15) * 64 + ksw]);
                fl_[m] = *reinterpret_cast<const f16x8*>(&Al[cur][(wr * 64 + m * 16 + l15) * 64 + ksw]);
            }
            #pragma unroll
            for (int n = 0; n < 8; ++n)
                bf[n] = *reinterpret_cast<const f16x8*>(&Bt[(wc * 128 + n * 16 + l15) * 64 + ksw]);
            #pragma unroll
            for (int m = 0; m < 4; ++m)
                #pragma unroll
                for (int n = 0; n < 8; ++n) {
                    acc[m][n] = MFMA16(fh[m],  bf[n], acc[m][n]);
                    acc[m][n] = MFMA16(fl_[m], bf[n], acc[m][n]);
                }
        }

        asm volatile("s_waitcnt vmcnt(0)" ::: "memory");   // A regs landed (hidden under MFMA)
        WRITEA(cur ^ 1);
        SBAR();                                            // B consumed by all; writes posted
        cur ^= 1;
    }

    float sw = wmax[0] / 7.0f + 1e-8f;
    float s1v = s1p[0];
    #pragma unroll
    for (int m = 0; m < 4; ++m)
        #pragma unroll
        for (int n = 0; n < 8; ++n)
            #pragma unroll
            for (int j = 0; j < 4; ++j) {
                int row = row0 + wr * 64 + m * 16 + l4 * 4 + j;
                int col = wc * 128 + n * 16 + l15;
                float h = sw * acc[m][n][j];
                float r = fmaxf(h, 0.f) / s1v;
                float qv = fminf(rintf(r), 15.f);
                A1[(size_t)row * 512 + col] = (signed char)qv;
                float fr = r - floorf(r);
                if (fabsf(fr - 0.5f) < FLAG_TOL) {
                    int p = atomicAdd(flagCnt, 1);
                    if (p < FLAG_CAP) flagList[p] = (unsigned)(row * 512 + col);
                }
            }
}

// ========== GEMM2: full-N i8 block (128 x 512), K=512, exact integer dot ==========
// A-LDS double-buffered via gld16 prefetch (counted vmcnt); B single-buffered.

__global__ __launch_bounds__(512, 2) void k_gemm2F(
    const signed char* __restrict__ A, const signed char* __restrict__ B,
    const float* __restrict__ wmax, const float* __restrict__ s1p, const float* __restrict__ s2p,
    signed char* __restrict__ A2, int* __restrict__ flagCnt, unsigned* __restrict__ flagList)
{
    constexpr int NT = 4;                    // 512B / 128B K-tiles
    __shared__ __align__(16) signed char As[2][128 * 128];  // 32 KB
    __shared__ __align__(16) signed char Bs[512 * 128];     // 64 KB

    const int t = threadIdx.x;
    const int lane = t & 63, w = t >> 6;
    const int wr = w >> 2, wc = w & 3;
    const int l15 = lane & 15, l4 = lane >> 4;
    const int row0 = blockIdx.x * 128;

    i32x4 acc[4][8];
    #pragma unroll
    for (int m = 0; m < 4; ++m)
        #pragma unroll
        for (int n = 0; n < 8; ++n) acc[m][n] = (i32x4){0, 0, 0, 0};

    const int lr = lane >> 3;
    const int lcb = ((lane & 7) ^ lr) * 16;  // swizzled 16B slot
    const signed char* Ab = A + (size_t)(row0 + lr) * 512 + lcb;
    const signed char* Bb = B + (size_t)lr * 512 + lcb;

    // prologue: A tile 0
    #pragma unroll
    for (int i = 0; i < 2; ++i) {
        int ch = w * 2 + i;                  // 16 chunks x 8 rows = 128
        gld16(Ab + (size_t)ch * 8 * 512, &As[0][ch * 1024]);
    }

    int cur = 0;
    for (int tt = 0; tt < NT; ++tt) {
        #pragma unroll
        for (int i = 0; i < 8; ++i) {
            int ch = w * 8 + i;              // 64 chunks x 8 rows = 512
            gld16(Bb + (size_t)ch * 8 * 512 + tt * 128, &Bs[ch * 1024]);
        }
        SCHEDB();
        int tn = (tt + 1 < NT) ? tt + 1 : tt;
        #pragma unroll
        for (int i = 0; i < 2; ++i) {
            int ch = w * 2 + i;
            gld16(Ab + (size_t)ch * 8 * 512 + tn * 128, &As[cur ^ 1][ch * 1024]);
        }
        SCHEDB();
        asm volatile("s_waitcnt vmcnt(2)" ::: "memory");   // A(tt) + B(tt) landed
        SBAR();

        #pragma unroll
        for (int kk = 0; kk < 2; ++kk) {
            int sl = kk * 4 + l4;                          // 16B slot 0..7
            int slw = (sl ^ (lane & 7)) * 16;
            i32x4 af[4], bf[8];
            #pragma unroll
            for (int m = 0; m < 4; ++m)
                af[m] = *reinterpret_cast<const i32x4*>(&As[cur][(wr * 64 + m * 16 + l15) * 128 + slw]);
            #pragma unroll
            for (int n = 0; n < 8; ++n)
                bf[n] = *reinterpret_cast<const i32x4*>(&Bs[(wc * 128 + n * 16 + l15) * 128 + slw]);
            #pragma unroll
            for (int m = 0; m < 4; ++m)
                #pragma unroll
                for (int n = 0; n < 8; ++n)
                    acc[m][n] = MFMAI8(af[m], bf[n], acc[m][n]);
        }

        SBAR();                                            // all done with Bs + As[cur]
        cur ^= 1;
    }

    double cs = (double)s1p[0] * (double)(wmax[0] / 7.0f + 1e-8f);
    double s2v = (double)s2p[0];
    #pragma unroll
    for (int m = 0; m < 4; ++m)
        #pragma unroll
        for (int n = 0; n < 8; ++n)
            #pragma unroll
            for (int j = 0; j < 4; ++j) {
                int row = row0 + wr * 64 + m * 16 + l4 * 4 + j;
                int col = wc * 128 + n * 16 + l15;
                double r = fmax((double)acc[m][n][j] * cs, 0.0) / s2v;
                double qv = fmin(rint(r), 15.0);
                A2[(size_t)row * 512 + col] = (signed char)qv;
                double fr = r - floor(r);
                if (fabs(fr - 0.5) < (double)FLAG_TOL && r < 16.0) {
                    int p = atomicAdd(flagCnt, 1);
                    if (p < FLAG_CAP) flagList[p] = (unsigned)(row * 512 + col);
                }
            }
}

// ---------------- fixups: BLAS-replicating sequential fp32 FMA ----------------

__global__ void k_fixup1(const float* __restrict__ X, const float* __restrict__ W1dq,
                         const float* __restrict__ s1p,
                         const int* __restrict__ flagCnt, const unsigned* __restrict__ flagList,
                         signed char* __restrict__ A1)
{
    int tid = blockIdx.x * blockDim.x + threadIdx.x;
    int nthr = gridDim.x * blockDim.x;
    int n = flagCnt[0];
    if (n > FLAG_CAP) n = FLAG_CAP;
    float s1 = s1p[0];
    for (int i = tid; i < n; i += nthr) {
        unsigned idx = flagList[i];
        int row = (int)(idx >> 9), col = (int)(idx & 511);
        const float* xr = X + (size_t)row * 784;
        const float* wr = W1dq + (size_t)col * 784;
        float acc = 0.f;
        for (int k = 0; k < 784; ++k)
            acc = fmaf(xr[k], wr[k], acc);       // k-ascending, single acc: BLAS order
        float tq = fmaxf(acc, 0.f) / s1;
        float code = fminf(rintf(tq), 15.f);
        A1[(size_t)row * 512 + col] = (signed char)code;
    }
}

__global__ void k_fixup2(const signed char* __restrict__ A1, const float* __restrict__ W2dq,
                         const float* __restrict__ s1p, const float* __restrict__ s2p,
                         const int* __restrict__ flagCnt, const unsigned* __restrict__ flagList,
                         signed char* __restrict__ A2)
{
    int tid = blockIdx.x * blockDim.x + threadIdx.x;
    int nthr = gridDim.x * blockDim.x;
    int n = flagCnt[0];
    if (n > FLAG_CAP) n = FLAG_CAP;
    float s1 = s1p[0], s2 = s2p[0];
    for (int i = tid; i < n; i += nthr) {
        unsigned idx = flagList[i];
        int row = (int)(idx >> 9), col = (int)(idx & 511);
        const signed char* ar = A1 + (size_t)row * 512;
        const float* wr = W2dq + (size_t)col * 512;
        float acc = 0.f;
        for (int k = 0; k < 512; ++k) {
            float adq = (float)ar[k] * s1;       // fp32 dequant, == ref
            acc = fmaf(adq, wr[k], acc);
        }
        float tq = fmaxf(acc, 0.f) / s2;
        float code = fminf(rintf(tq), 15.f);
        A2[(size_t)row * 512 + col] = (signed char)code;
    }
}

// ---------------- GEMM3: int8 [65536,512] @ [16,512]^T -> fp32 logits ----------------

__global__ __launch_bounds__(256) void k_gemm3i(
    const signed char* __restrict__ A2, const signed char* __restrict__ Q3,
    const float* __restrict__ wmax, const float* __restrict__ s2p,
    float* __restrict__ Out)
{
    __shared__ __align__(16) signed char As[256][80];   // 64B data + 16B pad
    __shared__ __align__(16) signed char Bs[16][80];

    const int t = threadIdx.x;
    const int row0 = blockIdx.x * 256;
    const int lane = t & 63, wv = t >> 6;

    i32x4 acc[4];
    #pragma unroll
    for (int m = 0; m < 4; ++m) acc[m] = (i32x4){0, 0, 0, 0};

    for (int k0 = 0; k0 < 512; k0 += 64) {
        #pragma unroll
        for (int i = 0; i < 4; ++i) {
            int f = t + 256 * i;
            int r = f >> 2, c = f & 3;
            *reinterpret_cast<uint4*>(&As[r][c * 16]) =
                *reinterpret_cast<const uint4*>(A2 + (size_t)(row0 + r) * 512 + k0 + c * 16);
        }
        if (t < 64) {
            int r = t >> 2, c = t & 3;
            *reinterpret_cast<uint4*>(&Bs[r][c * 16]) =
                *reinterpret_cast<const uint4*>(Q3 + (size_t)r * 512 + k0 + c * 16);
        }
        __syncthreads();

        i32x4 bf = *reinterpret_cast<const i32x4*>(&Bs[lane & 15][(lane >> 4) * 16]);
        #pragma unroll
        for (int m = 0; m < 4; ++m) {
            i32x4 af = *reinterpret_cast<const i32x4*>(&As[wv * 64 + m * 16 + (lane & 15)][(lane >> 4) * 16]);
            acc[m] = MFMAI8(af, bf, acc[m]);
        }
        __syncthreads();
    }

    double cs = (double)s2p[0] * (double)(wmax[0] / 7.0f + 1e-8f);
    #pragma unroll
    for (int m = 0; m < 4; ++m)
        #pragma unroll
        for (int j = 0; j < 4; ++j) {
            int row = row0 + wv * 64 + m * 16 + (lane >> 4) * 4 + j;
            int col = lane & 15;
            if (col < 10)
                Out[(size_t)row * 10 + col] = (float)((double)acc[m][j] * cs);
        }
}

// ---------------- launch ----------------

extern "C" void kernel_launch(void* const* d_in, const int* in_sizes, int n_in,
                              void* d_out, int out_size, void* d_ws, size_t ws_size,
                              hipStream_t stream)
{
    (void)in_sizes; (void)n_in; (void)out_size; (void)ws_size;

    const float* X  = (const float*)d_in[0];
    const float* W1 = (const float*)d_in[1];
    const float* W2 = (const float*)d_in[2];
    const float* W3 = (const float*)d_in[3];
    const float* s1 = (const float*)d_in[4];
    const float* s2 = (const float*)d_in[5];
    float* Out = (float*)d_out;

    char* ws = (char*)d_ws;
    float* maxes     = (float*)ws;
    int*   cnts      = (int*)(ws + 16);
    f16*   q1h       = (f16*)(ws + (size_t)(1u << 20));              // 852992 B
    float* w1dq      = (float*)(ws + (size_t)(2u << 20));            // 1605632 B
    float* w2dq      = (float*)(ws + (size_t)(4u << 20));            // 1048576 B
    signed char* q2i = (signed char*)(ws + (size_t)(6u << 20));      // 262144 B
    signed char* q3i = (signed char*)(ws + (size_t)(6u << 20) + 300000);  // 8192 B
    signed char* a1  = (signed char*)(ws + (size_t)(8u << 20));      // 32 MB
    signed char* a2  = (signed char*)(ws + (size_t)(40u << 20));     // 32 MB
    unsigned* fl1    = (unsigned*)(ws + (size_t)(72u << 20));        // 4 MB
    unsigned* fl2    = (unsigned*)(ws + (size_t)(76u << 20));        // 4 MB

    k_zero<<<1, 64, 0, stream>>>(maxes, cnts);
    k_absmax<<<256, 256, 0, stream>>>(W1, 512 * 784, maxes + 0);
    k_absmax<<<256, 256, 0, stream>>>(W2, 512 * 512, maxes + 1);
    k_absmax<<<8, 256, 0, stream>>>(W3, 10 * 512, maxes + 2);
    k_quantw1<<<(512 * 832 + 255) / 256, 256, 0, stream>>>(W1, maxes + 0, w1dq, q1h);
    k_quantw2<<<(512 * 512 + 255) / 256, 256, 0, stream>>>(W2, maxes + 1, q2i, w2dq, 512 * 512);
    k_quantw3<<<(16 * 512 + 255) / 256, 256, 0, stream>>>(W3, maxes + 2, q3i);

    k_gemm1F<<<512, 512, 0, stream>>>(X, q1h, maxes + 0, s1, a1, cnts + 0, fl1);
    k_fixup1<<<512, 256, 0, stream>>>(X, w1dq, s1, cnts + 0, fl1, a1);
    k_gemm2F<<<512, 512, 0, stream>>>(a1, q2i, maxes + 1, s1, s2, a2, cnts + 1, fl2);
    k_fixup2<<<512, 256, 0, stream>>>(a1, w2dq, s1, s2, cnts + 1, fl2, a2);
    k_gemm3i<<<256, 256, 0, stream>>>(a2, q3i, maxes + 2, s2, Out);
}